// Round 4
// baseline (479.293 us; speedup 1.0000x reference)
//
#include <hip/hip_runtime.h>

#define TLEN 2048
#define DM 1024
#define NH 8
#define HD 128

typedef unsigned short u16;
typedef __bf16 bf16_t;
typedef bf16_t bf16x8 __attribute__((ext_vector_type(8)));
typedef float f32x4 __attribute__((ext_vector_type(4)));
typedef unsigned short ushort8 __attribute__((ext_vector_type(8)));

union U16x8 { uint4 u4; ushort8 us; bf16x8 bf; };

__device__ __forceinline__ u16 f2bf(float f){
  unsigned u = __float_as_uint(f);
  u += 0x7FFFu + ((u>>16)&1u);
  return (u16)(u>>16);
}
__device__ __forceinline__ float bf2f(u16 u){ return __uint_as_float(((unsigned)u)<<16); }

#define MFMA16 __builtin_amdgcn_mfma_f32_16x16x32_bf16

// ---------------- elementwise cast f32 -> bf16 ----------------
__global__ void cast_f32_bf16(const float* __restrict__ in, u16* __restrict__ out, int n){
  int i = (blockIdx.x*256 + threadIdx.x)*8;
  if (i >= n) return;
  float4 a = *(const float4*)&in[i];
  float4 b = *(const float4*)&in[i+4];
  U16x8 r;
  r.us[0]=f2bf(a.x); r.us[1]=f2bf(a.y); r.us[2]=f2bf(a.z); r.us[3]=f2bf(a.w);
  r.us[4]=f2bf(b.x); r.us[5]=f2bf(b.y); r.us[6]=f2bf(b.z); r.us[7]=f2bf(b.w);
  *(uint4*)&out[i] = r.u4;
}

// ---------------- split cast: f32 -> bf16 hi + bf16 lo ----------------
__global__ void precast_hilo(const float* __restrict__ in, u16* __restrict__ hi, u16* __restrict__ lo, int n){
  int i = (blockIdx.x*256 + threadIdx.x)*8;
  if (i >= n) return;
  float4 a = *(const float4*)&in[i];
  float4 b = *(const float4*)&in[i+4];
  float v[8] = {a.x,a.y,a.z,a.w,b.x,b.y,b.z,b.w};
  U16x8 rh, rl;
  #pragma unroll
  for (int e=0;e<8;e++){
    u16 h = f2bf(v[e]);
    rh.us[e] = h;
    rl.us[e] = f2bf(v[e] - bf2f(h));
  }
  *(uint4*)&hi[i] = rh.u4;
  *(uint4*)&lo[i] = rl.u4;
}

// ------------- transpose + cast: in f32 [R][C] -> out bf16 [C][R] -------------
__global__ void transpose_cast(const float* __restrict__ in, u16* __restrict__ out, int R, int C){
  __shared__ float t[64][65];
  int r0 = blockIdx.y*64, c0 = blockIdx.x*64;
  int tid = threadIdx.x;
  int r = tid>>2, q = tid&3;
  const float* ip = in + (size_t)(r0+r)*C + c0 + q*16;
  #pragma unroll
  for (int i=0;i<4;i++){
    float4 v = *(const float4*)(ip + i*4);
    t[r][q*16+i*4+0]=v.x; t[r][q*16+i*4+1]=v.y; t[r][q*16+i*4+2]=v.z; t[r][q*16+i*4+3]=v.w;
  }
  __syncthreads();
  int oc = tid>>2;
  U16x8 lo, hi;
  #pragma unroll
  for (int i=0;i<8;i++) lo.us[i] = f2bf(t[q*16+i][oc]);
  #pragma unroll
  for (int i=0;i<8;i++) hi.us[i] = f2bf(t[q*16+8+i][oc]);
  u16* op = out + (size_t)(c0+oc)*R + r0 + q*16;
  *(uint4*)&op[0] = lo.u4;
  *(uint4*)&op[8] = hi.u4;
}

// ------------- bf16 GEMM: A[M][K] rm, Bt[N][K] rm, C = A@B (fp32 or bf16 out) -------------
__global__ __launch_bounds__(256) void gemm_bf16(const u16* __restrict__ A, const u16* __restrict__ Bt,
                                                 void* __restrict__ Cout, int M, int N, int K, int out_bf){
  __shared__ u16 As[128][40];
  __shared__ u16 Bs[128][40];
  int tid = threadIdx.x, lane = tid&63, w = tid>>6;
  int m0 = blockIdx.y*128, n0 = blockIdx.x*128;
  int wr = (w>>1)*64, wc = (w&1)*64;
  f32x4 acc[4][4];
  #pragma unroll
  for (int a=0;a<4;a++)
    #pragma unroll
    for (int b=0;b<4;b++) acc[a][b] = (f32x4){0.f,0.f,0.f,0.f};
  int lr = tid>>1, lc = (tid&1)*16;
  const u16* Ap = A + (size_t)(m0+lr)*K + lc;
  const u16* Bp = Bt + (size_t)(n0+lr)*K + lc;
  int l15 = lane&15, ksel = (lane>>4)*8;
  for (int kk=0; kk<K; kk+=32){
    uint4 av0 = *(const uint4*)(Ap+kk); uint4 av1 = *(const uint4*)(Ap+kk+8);
    uint4 bv0 = *(const uint4*)(Bp+kk); uint4 bv1 = *(const uint4*)(Bp+kk+8);
    __syncthreads();
    *(uint4*)&As[lr][lc] = av0; *(uint4*)&As[lr][lc+8] = av1;
    *(uint4*)&Bs[lr][lc] = bv0; *(uint4*)&Bs[lr][lc+8] = bv1;
    __syncthreads();
    bf16x8 a[4], b[4];
    #pragma unroll
    for (int f=0; f<4; f++){
      a[f] = *(const bf16x8*)&As[wr + 16*f + l15][ksel];
      b[f] = *(const bf16x8*)&Bs[wc + 16*f + l15][ksel];
    }
    #pragma unroll
    for (int fm=0; fm<4; fm++)
      #pragma unroll
      for (int fn=0; fn<4; fn++)
        acc[fm][fn] = MFMA16(a[fm], b[fn], acc[fm][fn], 0,0,0);
  }
  int rowoff = (lane>>4)*4;
  #pragma unroll
  for (int fm=0; fm<4; fm++)
    #pragma unroll
    for (int fn=0; fn<4; fn++)
      #pragma unroll
      for (int e=0; e<4; e++){
        size_t idx = (size_t)(m0+wr+16*fm+rowoff+e)*N + n0+wc+16*fn+l15;
        float v = acc[fm][fn][e];
        if (out_bf) ((u16*)Cout)[idx] = f2bf(v);
        else ((float*)Cout)[idx] = v;
      }
}

// ------------- small projections x@Wbeta, x@Wg -> [T][8] each -------------
__global__ void proj_small(const float* __restrict__ x, const float* __restrict__ Wb, const float* __restrict__ Wg,
                           float* __restrict__ xWb, float* __restrict__ xWg){
  int w = threadIdx.x>>6, lane = threadIdx.x&63;
  int t = blockIdx.x*4 + w;
  float accB[8], accG[8];
  #pragma unroll
  for (int o=0;o<8;o++){ accB[o]=0.f; accG[o]=0.f; }
  for (int k=lane; k<DM; k+=64){
    float xv = x[(size_t)t*DM + k];
    #pragma unroll
    for (int o=0;o<8;o++){ accB[o] += xv*Wb[k*8+o]; accG[o] += xv*Wg[k*8+o]; }
  }
  #pragma unroll
  for (int o=0;o<8;o++){
    float b = accB[o], g = accG[o];
    #pragma unroll
    for (int d=1; d<64; d<<=1){ b += __shfl_xor(b, d, 64); g += __shfl_xor(g, d, 64); }
    if (lane==0){ xWb[t*8+o] = b; xWg[t*8+o] = g; }
  }
}

// ------------- beta = 2*sigmoid, g = logsigmoid, G = cumsum (per head) -------------
__global__ void scan_g(const float* __restrict__ xWb, const float* __restrict__ xWg,
                       float* __restrict__ beta, float* __restrict__ G){
  int h = threadIdx.x>>6, lane = threadIdx.x&63;
  float off = 0.f;
  for (int tile=0; tile<TLEN/64; ++tile){
    int t = tile*64 + lane;
    float braw = xWb[t*8+h];
    beta[h*TLEN+t] = 2.f/(1.f+expf(-braw));
    float graw = xWg[t*8+h];
    float g = (graw < 0.f) ? (graw - log1pf(expf(graw))) : (-log1pf(expf(-graw)));
    #pragma unroll
    for (int d=1; d<64; d<<=1){ float n = __shfl_up(g, d, 64); if (lane>=d) g += n; }
    G[h*TLEN+t] = g + off;
    off += __shfl(g, 63, 64);
  }
}

// ------------- per-(t,head) RMS norm in place -------------
__global__ void rms_inplace(float* __restrict__ buf, const float* __restrict__ wn){
  int lane = threadIdx.x;
  int t = blockIdx.x>>3, h = blockIdx.x&7;
  size_t base = (size_t)t*DM + h*HD;
  float v0 = buf[base+lane], v1 = buf[base+64+lane];
  float ss = v0*v0 + v1*v1;
  #pragma unroll
  for (int d=1; d<64; d<<=1) ss += __shfl_xor(ss, d, 64);
  float f = rsqrtf(ss*(1.f/128.f) + 1e-6f);
  buf[base+lane] = v0*f*wn[lane];
  buf[base+64+lane] = v1*f*wn[64+lane];
}

// ------------- causal depthwise conv(4) + silu + per-head l2 norm -------------
__global__ void conv_silu_norm(const float* __restrict__ wpre, const float* __restrict__ cw,
                               float* __restrict__ wd){
  int t = blockIdx.x, tid = threadIdx.x;
  int c0 = tid*4;
  float cwa[4][4];
  #pragma unroll
  for (int c=0;c<4;c++){
    float4 v = *(const float4*)&cw[(c0+c)*4];
    cwa[c][0]=v.x; cwa[c][1]=v.y; cwa[c][2]=v.z; cwa[c][3]=v.w;
  }
  float acc[4] = {0.f,0.f,0.f,0.f};
  #pragma unroll
  for (int i=0;i<4;i++){
    int ti = t-3+i;
    if (ti >= 0){
      float4 xv = *(const float4*)&wpre[(size_t)ti*DM + c0];
      acc[0] += xv.x*cwa[0][i]; acc[1] += xv.y*cwa[1][i];
      acc[2] += xv.z*cwa[2][i]; acc[3] += xv.w*cwa[3][i];
    }
  }
  float s[4], ss = 0.f;
  #pragma unroll
  for (int c=0;c<4;c++){ s[c] = acc[c]/(1.f+__expf(-acc[c])); ss += s[c]*s[c]; }
  #pragma unroll
  for (int d=1; d<32; d<<=1) ss += __shfl_xor(ss, d, 64);
  float f = rsqrtf(ss + 1e-6f);
  float4 o = {s[0]*f, s[1]*f, s[2]*f, s[3]*f};
  *(float4*)&wd[(size_t)t*DM + c0] = o;
}

// ------------- gram: per (h,chunk) four 64x64 matrices via split-bf16 MFMA -------------
// plane 0: W.W^T  plane 1: W.K^T  plane 2: Q.W^T  plane 3: Q.K^T
__global__ __launch_bounds__(256) void gram_kernel(
    const u16* __restrict__ Whi, const u16* __restrict__ Wlo,
    const u16* __restrict__ Khi, const u16* __restrict__ Klo,
    const u16* __restrict__ Qhi, const u16* __restrict__ Qlo,
    float* __restrict__ G4){
  int h = blockIdx.x>>5, I = blockIdx.x&31, t0 = I*64;
  int tid = threadIdx.x, lane = tid&63, w = tid>>6;
  int l15 = lane&15, l4 = lane>>4;
  const u16 *Ah, *Al, *Bh, *Bl;
  if (w==0){ Ah=Whi; Al=Wlo; Bh=Whi; Bl=Wlo; }
  else if (w==1){ Ah=Whi; Al=Wlo; Bh=Khi; Bl=Klo; }
  else if (w==2){ Ah=Qhi; Al=Qlo; Bh=Whi; Bl=Wlo; }
  else { Ah=Qhi; Al=Qlo; Bh=Khi; Bl=Klo; }
  size_t rowbase = (size_t)t0*DM + h*HD;
  f32x4 acc[4][4];
  #pragma unroll
  for (int a=0;a<4;a++)
    #pragma unroll
    for (int b=0;b<4;b++) acc[a][b] = (f32x4){0.f,0.f,0.f,0.f};
  #pragma unroll 1
  for (int ks=0; ks<4; ++ks){
    bf16x8 ah[4], al[4], bh[4], bl[4];
    #pragma unroll
    for (int f=0; f<4; f++){
      size_t off = rowbase + (size_t)(16*f + l15)*DM + ks*32 + l4*8;
      ah[f] = *(const bf16x8*)(Ah + off);
      al[f] = *(const bf16x8*)(Al + off);
      bh[f] = *(const bf16x8*)(Bh + off);
      bl[f] = *(const bf16x8*)(Bl + off);
    }
    #pragma unroll
    for (int fm=0; fm<4; fm++)
      #pragma unroll
      for (int fn=0; fn<4; fn++){
        acc[fm][fn] = MFMA16(ah[fm], bh[fn], acc[fm][fn], 0,0,0);
        acc[fm][fn] = MFMA16(ah[fm], bl[fn], acc[fm][fn], 0,0,0);
        acc[fm][fn] = MFMA16(al[fm], bh[fn], acc[fm][fn], 0,0,0);
      }
  }
  float* out = G4 + ((size_t)(h*32+I)*4 + w)*4096;
  #pragma unroll
  for (int fm=0; fm<4; fm++)
    #pragma unroll
    for (int fn=0; fn<4; fn++)
      #pragma unroll
      for (int e=0; e<4; e++)
        out[(16*fm + l4*4 + e)*64 + 16*fn + l15] = acc[fm][fn][e];
}

// ------------- solve: per (h,chunk) forward substitution for b_k, b_w -------------
// reads planes 0 (Sww), 1 (WK); writes beta-scaled solutions back over planes 0 (Xk), 1 (Xw)
__global__ __launch_bounds__(128) void solve_kernel(float* __restrict__ G4, const float* __restrict__ betaB){
  int h = blockIdx.x>>5, I = blockIdx.x&31, t0 = I*64;
  int tid = threadIdx.x;
  __shared__ float M[64][68];
  __shared__ float X[64][132];
  __shared__ float bet[64];
  float* base = G4 + (size_t)(h*32+I)*4*4096;
  float* Sww = base;
  float* WK  = base + 4096;
  if (tid < 64) bet[tid] = betaB[h*TLEN + t0 + tid];
  __syncthreads();
  #pragma unroll 1
  for (int i=0;i<32;i++){
    int idx = i*128 + tid;
    int s = idx>>6, r = idx&63;
    float sww = Sww[idx];
    M[s][r] = (s>r) ? sww*bet[r] : ((s==r)?1.f:0.f);
    X[s][64+r] = (s>r) ? sww : 0.f;
    X[s][r]    = (s>r) ? WK[idx] : 0.f;
  }
  __syncthreads();
  {
    int c = tid;
    for (int s=1; s<64; ++s){
      float acc = X[s][c];
      int r = 0;
      for (; r+4<=s; r+=4)
        acc -= M[s][r]*X[r][c] + M[s][r+1]*X[r+1][c] + M[s][r+2]*X[r+2][c] + M[s][r+3]*X[r+3][c];
      for (; r<s; ++r) acc -= M[s][r]*X[r][c];
      X[s][c] = acc;
    }
    #pragma unroll 1
    for (int s=0;s<64;++s) X[s][c] *= bet[s];
  }
  __syncthreads();
  #pragma unroll 1
  for (int i=0;i<32;i++){
    int idx = i*128 + tid;
    int s = idx>>6, j = idx&63;
    Sww[idx] = X[s][j];        // Xk = beta_s * b_k[s][j]   (strictly lower)
    WK[idx]  = X[s][64+j];     // Xw = beta_s * b_w[s][j]   (strictly lower)
  }
}

// ------------- post: per (h,chunk) A_diag, C~, Qtilde, Ktilde -------------
__global__ __launch_bounds__(256) void post_kernel(
    const float* __restrict__ G4, const float* __restrict__ Qn, const float* __restrict__ Kn,
    const u16* __restrict__ Whi, const float* __restrict__ betaB,
    float* __restrict__ Adiag, u16* __restrict__ Qt, u16* __restrict__ Ktb){
  int h = blockIdx.x>>5, I = blockIdx.x&31, t0 = I*64;
  int tid = threadIdx.x;
  const float* base = G4 + (size_t)(h*32+I)*4*4096;
  const float* Xk_g = base;
  const float* Xw_g = base + 4096;
  const float* QW_g = base + 2*4096;
  const float* QK_g = base + 3*4096;
  __shared__ float DT[64][64];   // D~T[s][t] = (s<=t)? (q_t.w_s) : 0 ; later reused as W bf16
  __shared__ float Xk[64][64];
  __shared__ float Xw[64][64];   // later C~T[s][t]
  #pragma unroll 1
  for (int i=0;i<16;i++){
    int idx = i*256 + tid;
    int a = idx>>6, b = idx&63;          // a=s, b=t (or col)
    DT[a][b] = (a<=b) ? QW_g[b*64+a] : 0.f;
    Xk[a][b] = Xk_g[idx];
    Xw[a][b] = Xw_g[idx];
  }
  __syncthreads();
  // P1: A_diag[t][j] = QK[t][j] - sum_s DT[s][t]*Xk[s][j]   (zeros enforce j<s<=t)
  {
    int t = tid>>2, jg = tid&3;
    #pragma unroll 1
    for (int j16=0;j16<16;j16++){
      int j = jg*16 + j16;
      float acc = QK_g[t*64+j];
      #pragma unroll 4
      for (int s=0;s<64;s++) acc -= DT[s][t]*Xk[s][j];
      Adiag[((size_t)(h*32+I)*64 + t)*64 + j] = acc;
    }
  }
  // P2: C~T[s][t] = beta_s * ( DT[s][t] - sum_r DT[r][t]*Xw[r][s] )
  float creg[16];
  {
    int t = tid>>2, sg = tid&3;
    #pragma unroll 1
    for (int s16=0;s16<16;s16++){
      int s = sg*16 + s16;
      float c = DT[s][t];
      #pragma unroll 4
      for (int r=0;r<64;r++) c -= DT[r][t]*Xw[r][s];
      creg[s16] = c * betaB[h*TLEN + t0 + s];
    }
  }
  __syncthreads();
  {
    int t = tid>>2, sg = tid&3;
    #pragma unroll
    for (int s16=0;s16<16;s16++){ int s = sg*16+s16; Xw[s][t] = creg[s16]; }
  }
  __syncthreads();
  // load W (bf16 hi plane) over DT
  u16* Wb = (u16*)&DT[0][0];   // [64][128] bf16
  #pragma unroll
  for (int i=0;i<4;i++){
    int c = i*256 + tid;       // 1024 chunks of 8 u16
    int r = c>>4, p = c&15;
    *(uint4*)&Wb[r*128 + p*8] = *(const uint4*)(Whi + (size_t)(t0+r)*DM + h*HD + p*8);
  }
  __syncthreads();
  // P3: Ktilde[j] = K[j] - sum_s Xk[s][j]*W[s]
  {
    int j = tid>>2, q = tid&3;
    float acc[32];
    const float* kp = Kn + (size_t)(t0+j)*DM + h*HD + q*32;
    #pragma unroll
    for (int a4=0;a4<8;a4++){
      float4 kv = *(const float4*)(kp + a4*4);
      acc[a4*4+0]=kv.x; acc[a4*4+1]=kv.y; acc[a4*4+2]=kv.z; acc[a4*4+3]=kv.w;
    }
    #pragma unroll 1
    for (int s=0;s<64;++s){
      float xv = Xk[s][j];
      const u16* wr = &Wb[s*128 + q*32];
      #pragma unroll
      for (int a=0;a<32;a++) acc[a] -= xv * bf2f(wr[a]);
    }
    u16* kout = Ktb + ((size_t)h*TLEN + t0 + j)*HD + q*32;
    #pragma unroll
    for (int a8=0;a8<4;a8++){
      U16x8 u;
      #pragma unroll
      for (int e=0;e<8;e++) u.us[e] = f2bf(acc[a8*8+e]);
      *(uint4*)&kout[a8*8] = u.u4;
    }
  }
  // P4: Qtilde[t] = Q[t] - sum_s C~T[s][t]*W[s]
  {
    int t = tid>>2, q = tid&3;
    float acc[32];
    const float* qp = Qn + (size_t)(t0+t)*DM + h*HD + q*32;
    #pragma unroll
    for (int a4=0;a4<8;a4++){
      float4 qv = *(const float4*)(qp + a4*4);
      acc[a4*4+0]=qv.x; acc[a4*4+1]=qv.y; acc[a4*4+2]=qv.z; acc[a4*4+3]=qv.w;
    }
    #pragma unroll 1
    for (int s=0;s<64;++s){
      float cm = Xw[s][t];
      const u16* wr = &Wb[s*128 + q*32];
      #pragma unroll
      for (int a=0;a<32;a++) acc[a] -= cm * bf2f(wr[a]);
    }
    u16* qout = Qt + ((size_t)h*TLEN + t0 + t)*HD + q*32;
    #pragma unroll
    for (int a8=0;a8<4;a8++){
      U16x8 u;
      #pragma unroll
      for (int e=0;e<8;e++) u.us[e] = f2bf(acc[a8*8+e]);
      *(uint4*)&qout[a8*8] = u.u4;
    }
  }
}

// ------------- fused windowed attention: per (head, chunk I) -------------
// window cols 0..63 = chunk I-1 (masked out for I==0), cols 64..127 = diag chunk I
__global__ __launch_bounds__(256) void attn_win(const u16* __restrict__ Qt, const u16* __restrict__ Ktb,
    const float* __restrict__ Adiag, const float* __restrict__ G,
    const u16* __restrict__ Vt, u16* __restrict__ obuf){
  int h = blockIdx.x>>5, I = blockIdx.x&31;
  int tid = threadIdx.x, lane = tid&63, w = tid>>6;
  int l15 = lane&15, l4 = lane>>4;
  __shared__ float S[64][136];
  __shared__ u16 P[64][136];

  // phase A: S lower half = Qtilde_I @ Ktilde_{I-1}^T via MFMA
  if (I > 0){
    f32x4 acc4[4];
    #pragma unroll
    for (int f=0;f<4;f++) acc4[f] = (f32x4){0.f,0.f,0.f,0.f};
    #pragma unroll 1
    for (int ks=0; ks<4; ++ks){
      bf16x8 af = *(const bf16x8*)(Qt + ((size_t)h*TLEN + I*64 + 16*w + l15)*HD + ks*32 + l4*8);
      #pragma unroll
      for (int fn=0; fn<4; ++fn){
        bf16x8 bf = *(const bf16x8*)(Ktb + ((size_t)h*TLEN + (I-1)*64 + 16*fn + l15)*HD + ks*32 + l4*8);
        acc4[fn] = MFMA16(af, bf, acc4[fn], 0,0,0);
      }
    }
    #pragma unroll
    for (int fn=0; fn<4; ++fn)
      #pragma unroll
      for (int e=0;e<4;e++)
        S[16*w + l4*4 + e][16*fn + l15] = acc4[fn][e];
  }
  // phase B: diag copy (and zero lower half when I==0)
  #pragma unroll 1
  for (int i=0;i<16;i++){
    int idx = i*256 + tid;
    int tq = idx>>6, j = idx&63;
    S[tq][64+j] = Adiag[((size_t)(h*32+I)*64 + tq)*64 + j];
    if (I == 0) S[tq][j] = 0.f;
  }
  __syncthreads();

  // phase C: softmax with FoX gates; 4 threads per row, 32 cols each
  {
    int r = tid>>2, qd = tid&3, c0 = qd*32;
    int t = I*64 + r;
    float Gt = G[h*TLEN + t];
    const float scale = 0.08838834764831845f;
    int base = I*64 - 64;
    float lg[32];
    float mx = -1e30f;
    #pragma unroll
    for (int e=0;e<32;e++){
      int c = c0 + e;
      int j = base + c;
      float gj = G[h*TLEN + (j<0?0:j)];
      float v = (j>=0 && j<=t) ? (S[r][c]*scale + Gt - gj) : -1e30f;
      lg[e] = v;
      mx = fmaxf(mx, v);
    }
    mx = fmaxf(mx, __shfl_xor(mx, 1, 64));
    mx = fmaxf(mx, __shfl_xor(mx, 2, 64));
    float sum = 0.f;
    #pragma unroll
    for (int e=0;e<32;e++){ float p = __expf(lg[e]-mx); lg[e] = p; sum += p; }
    sum += __shfl_xor(sum, 1, 64);
    sum += __shfl_xor(sum, 2, 64);
    float inv = 1.f/sum;
    #pragma unroll
    for (int e8=0;e8<4;e8++){
      U16x8 u;
      #pragma unroll
      for (int e=0;e<8;e++) u.us[e] = f2bf(lg[e8*8+e]*inv);
      *(uint4*)&P[r][c0 + e8*8] = u.u4;
    }
  }
  __syncthreads();

  // phase D: O = P @ V_window via MFMA
  {
    f32x4 acc[8];
    #pragma unroll
    for (int f=0;f<8;f++) acc[f] = (f32x4){0.f,0.f,0.f,0.f};
    #pragma unroll 1
    for (int ks=0; ks<4; ++ks){
      bf16x8 pa = *(const bf16x8*)&P[16*w + l15][ks*32 + l4*8];
      int jb = (I-1)*64 + ks*32 + l4*8;
      if (jb < 0) jb = 0;   // masked cols (P==0) read valid memory
      #pragma unroll
      for (int fd=0; fd<8; ++fd){
        bf16x8 vb = *(const bf16x8*)(Vt + ((size_t)(h*HD + l15 + 16*fd))*TLEN + jb);
        acc[fd] = MFMA16(pa, vb, acc[fd], 0,0,0);
      }
    }
    #pragma unroll
    for (int fd=0; fd<8; ++fd)
      #pragma unroll
      for (int e=0;e<4;e++)
        obuf[(size_t)(I*64 + 16*w + l4*4 + e)*DM + h*HD + l15 + 16*fd] = f2bf(acc[fd][e]);
  }
}

extern "C" void kernel_launch(void* const* d_in, const int* in_sizes, int n_in,
                              void* d_out, int out_size, void* d_ws, size_t ws_size,
                              hipStream_t stream){
  const float* x     = (const float*)d_in[0];
  const float* Wq    = (const float*)d_in[1];
  const float* Wk    = (const float*)d_in[2];
  const float* Wv    = (const float*)d_in[3];
  const float* Ww    = (const float*)d_in[4];
  const float* Wbeta = (const float*)d_in[5];
  const float* Wg    = (const float*)d_in[6];
  const float* Wo    = (const float*)d_in[7];
  const float* convw = (const float*)d_in[8];
  const float* qnw   = (const float*)d_in[9];
  const float* knw   = (const float*)d_in[10];

  char* ws = (char*)d_ws;
  size_t off = 0;
  auto take = [&](size_t n)->char*{ char* p = ws + off; off += (n + 255) & ~(size_t)255; return p; };

  u16*  xb    = (u16*)take((size_t)TLEN*DM*2);      // aliased later by obuf
  u16*  WqT   = (u16*)take((size_t)DM*DM*2);
  u16*  WkT   = (u16*)take((size_t)DM*DM*2);
  u16*  WvT   = (u16*)take((size_t)DM*DM*2);
  u16*  WwT   = (u16*)take((size_t)DM*DM*2);
  u16*  WoT   = (u16*)take((size_t)DM*DM*2);
  float* Qn   = (float*)take((size_t)TLEN*DM*4);
  float* Kn   = (float*)take((size_t)TLEN*DM*4);
  float* Vraw = (float*)take((size_t)TLEN*DM*4);    // aliased later by Adiag
  float* Wpre = (float*)take((size_t)TLEN*DM*4);
  float* Wdir = (float*)take((size_t)TLEN*DM*4);
  u16*  Vt    = (u16*)take((size_t)DM*TLEN*2);
  float* xWb  = (float*)take((size_t)TLEN*8*4);
  float* xWg  = (float*)take((size_t)TLEN*8*4);
  float* betaB= (float*)take((size_t)NH*TLEN*4);
  float* GB   = (float*)take((size_t)NH*TLEN*4);
  u16*  Qt    = (u16*)take((size_t)NH*TLEN*HD*2);
  u16*  Ktb   = (u16*)take((size_t)NH*TLEN*HD*2);
  u16*  Whi   = (u16*)take((size_t)TLEN*DM*2);
  u16*  Wlo   = (u16*)take((size_t)TLEN*DM*2);
  u16*  Khi   = (u16*)take((size_t)TLEN*DM*2);
  u16*  Klo   = (u16*)take((size_t)TLEN*DM*2);
  u16*  Qhi   = (u16*)take((size_t)TLEN*DM*2);
  u16*  Qlo   = (u16*)take((size_t)TLEN*DM*2);
  float* G4   = (float*)take((size_t)NH*32*4*64*64*4);   // 16 MB

  float* Adiag = (float*)Vraw;   // 4 MB needed; Vraw dead after Vt transpose
  u16*  obuf  = xb;              // 4 MB; xb dead after the 4 projection GEMMs

  cast_f32_bf16<<<dim3(TLEN*DM/(256*8)), dim3(256), 0, stream>>>(x, xb, TLEN*DM);
  transpose_cast<<<dim3(16,16), dim3(256), 0, stream>>>(Wq, WqT, DM, DM);
  transpose_cast<<<dim3(16,16), dim3(256), 0, stream>>>(Wk, WkT, DM, DM);
  transpose_cast<<<dim3(16,16), dim3(256), 0, stream>>>(Wv, WvT, DM, DM);
  transpose_cast<<<dim3(16,16), dim3(256), 0, stream>>>(Ww, WwT, DM, DM);
  transpose_cast<<<dim3(16,16), dim3(256), 0, stream>>>(Wo, WoT, DM, DM);

  gemm_bf16<<<dim3(DM/128, TLEN/128), dim3(256), 0, stream>>>(xb, WqT, Qn, TLEN, DM, DM, 0);
  gemm_bf16<<<dim3(DM/128, TLEN/128), dim3(256), 0, stream>>>(xb, WkT, Kn, TLEN, DM, DM, 0);
  gemm_bf16<<<dim3(DM/128, TLEN/128), dim3(256), 0, stream>>>(xb, WvT, Vraw, TLEN, DM, DM, 0);
  gemm_bf16<<<dim3(DM/128, TLEN/128), dim3(256), 0, stream>>>(xb, WwT, Wpre, TLEN, DM, DM, 0);

  proj_small<<<dim3(TLEN/4), dim3(256), 0, stream>>>(x, Wbeta, Wg, xWb, xWg);
  scan_g<<<dim3(1), dim3(512), 0, stream>>>(xWb, xWg, betaB, GB);

  rms_inplace<<<dim3(TLEN*NH), dim3(64), 0, stream>>>(Qn, qnw);
  rms_inplace<<<dim3(TLEN*NH), dim3(64), 0, stream>>>(Kn, knw);
  conv_silu_norm<<<dim3(TLEN), dim3(256), 0, stream>>>(Wpre, convw, Wdir);
  transpose_cast<<<dim3(16,32), dim3(256), 0, stream>>>(Vraw, Vt, TLEN, DM);   // Vraw dead after this

  precast_hilo<<<dim3(TLEN*DM/(256*8)), dim3(256), 0, stream>>>(Wdir, Whi, Wlo, TLEN*DM);
  precast_hilo<<<dim3(TLEN*DM/(256*8)), dim3(256), 0, stream>>>(Kn,   Khi, Klo, TLEN*DM);
  precast_hilo<<<dim3(TLEN*DM/(256*8)), dim3(256), 0, stream>>>(Qn,   Qhi, Qlo, TLEN*DM);

  gram_kernel<<<dim3(256), dim3(256), 0, stream>>>(Whi, Wlo, Khi, Klo, Qhi, Qlo, G4);
  solve_kernel<<<dim3(256), dim3(128), 0, stream>>>(G4, betaB);
  post_kernel<<<dim3(256), dim3(256), 0, stream>>>(G4, Qn, Kn, Whi, betaB, Adiag, Qt, Ktb);

  attn_win<<<dim3(256), dim3(256), 0, stream>>>(Qt, Ktb, Adiag, GB, Vt, obuf);

  // FINAL PROJECTION — d_out is FLOAT32 (reference output dtype), not bf16.
  gemm_bf16<<<dim3(DM/128, TLEN/128), dim3(256), 0, stream>>>(obuf, WoT, d_out, TLEN, DM, DM, 0);
}

// Round 5
// 427.756 us; speedup vs baseline: 1.1205x; 1.1205x over previous
//
#include <hip/hip_runtime.h>

#define TLEN 2048
#define DM 1024
#define NH 8
#define HD 128

typedef unsigned short u16;
typedef __bf16 bf16_t;
typedef bf16_t bf16x8 __attribute__((ext_vector_type(8)));
typedef float f32x4 __attribute__((ext_vector_type(4)));
typedef unsigned short ushort8 __attribute__((ext_vector_type(8)));

union U16x8 { uint4 u4; ushort8 us; bf16x8 bf; };

__device__ __forceinline__ u16 f2bf(float f){
  unsigned u = __float_as_uint(f);
  u += 0x7FFFu + ((u>>16)&1u);
  return (u16)(u>>16);
}
__device__ __forceinline__ float bf2f(u16 u){ return __uint_as_float(((unsigned)u)<<16); }

#define MFMA16 __builtin_amdgcn_mfma_f32_16x16x32_bf16

// ---------------- elementwise cast f32 -> bf16 ----------------
__global__ void cast_f32_bf16(const float* __restrict__ in, u16* __restrict__ out, int n){
  int i = (blockIdx.x*256 + threadIdx.x)*8;
  if (i >= n) return;
  float4 a = *(const float4*)&in[i];
  float4 b = *(const float4*)&in[i+4];
  U16x8 r;
  r.us[0]=f2bf(a.x); r.us[1]=f2bf(a.y); r.us[2]=f2bf(a.z); r.us[3]=f2bf(a.w);
  r.us[4]=f2bf(b.x); r.us[5]=f2bf(b.y); r.us[6]=f2bf(b.z); r.us[7]=f2bf(b.w);
  *(uint4*)&out[i] = r.u4;
}

// ---------------- split cast: f32 -> bf16 hi + bf16 lo ----------------
__global__ void precast_hilo(const float* __restrict__ in, u16* __restrict__ hi, u16* __restrict__ lo, int n){
  int i = (blockIdx.x*256 + threadIdx.x)*8;
  if (i >= n) return;
  float4 a = *(const float4*)&in[i];
  float4 b = *(const float4*)&in[i+4];
  float v[8] = {a.x,a.y,a.z,a.w,b.x,b.y,b.z,b.w};
  U16x8 rh, rl;
  #pragma unroll
  for (int e=0;e<8;e++){
    u16 h = f2bf(v[e]);
    rh.us[e] = h;
    rl.us[e] = f2bf(v[e] - bf2f(h));
  }
  *(uint4*)&hi[i] = rh.u4;
  *(uint4*)&lo[i] = rl.u4;
}

// ------------- transpose + cast: in f32 [R][C] -> out bf16 [C][R] -------------
__global__ void transpose_cast(const float* __restrict__ in, u16* __restrict__ out, int R, int C){
  __shared__ float t[64][65];
  int r0 = blockIdx.y*64, c0 = blockIdx.x*64;
  int tid = threadIdx.x;
  int r = tid>>2, q = tid&3;
  const float* ip = in + (size_t)(r0+r)*C + c0 + q*16;
  #pragma unroll
  for (int i=0;i<4;i++){
    float4 v = *(const float4*)(ip + i*4);
    t[r][q*16+i*4+0]=v.x; t[r][q*16+i*4+1]=v.y; t[r][q*16+i*4+2]=v.z; t[r][q*16+i*4+3]=v.w;
  }
  __syncthreads();
  int oc = tid>>2;
  U16x8 lo, hi;
  #pragma unroll
  for (int i=0;i<8;i++) lo.us[i] = f2bf(t[q*16+i][oc]);
  #pragma unroll
  for (int i=0;i<8;i++) hi.us[i] = f2bf(t[q*16+8+i][oc]);
  u16* op = out + (size_t)(c0+oc)*R + r0 + q*16;
  *(uint4*)&op[0] = lo.u4;
  *(uint4*)&op[8] = hi.u4;
}

// ------------- bf16 GEMM: A[M][K] rm, Bt[N][K] rm, C = A@B (fp32 or bf16 out) -------------
__global__ __launch_bounds__(256) void gemm_bf16(const u16* __restrict__ A, const u16* __restrict__ Bt,
                                                 void* __restrict__ Cout, int M, int N, int K, int out_bf){
  __shared__ u16 As[128][40];
  __shared__ u16 Bs[128][40];
  int tid = threadIdx.x, lane = tid&63, w = tid>>6;
  int m0 = blockIdx.y*128, n0 = blockIdx.x*128;
  int wr = (w>>1)*64, wc = (w&1)*64;
  f32x4 acc[4][4];
  #pragma unroll
  for (int a=0;a<4;a++)
    #pragma unroll
    for (int b=0;b<4;b++) acc[a][b] = (f32x4){0.f,0.f,0.f,0.f};
  int lr = tid>>1, lc = (tid&1)*16;
  const u16* Ap = A + (size_t)(m0+lr)*K + lc;
  const u16* Bp = Bt + (size_t)(n0+lr)*K + lc;
  int l15 = lane&15, ksel = (lane>>4)*8;
  for (int kk=0; kk<K; kk+=32){
    uint4 av0 = *(const uint4*)(Ap+kk); uint4 av1 = *(const uint4*)(Ap+kk+8);
    uint4 bv0 = *(const uint4*)(Bp+kk); uint4 bv1 = *(const uint4*)(Bp+kk+8);
    __syncthreads();
    *(uint4*)&As[lr][lc] = av0; *(uint4*)&As[lr][lc+8] = av1;
    *(uint4*)&Bs[lr][lc] = bv0; *(uint4*)&Bs[lr][lc+8] = bv1;
    __syncthreads();
    bf16x8 a[4], b[4];
    #pragma unroll
    for (int f=0; f<4; f++){
      a[f] = *(const bf16x8*)&As[wr + 16*f + l15][ksel];
      b[f] = *(const bf16x8*)&Bs[wc + 16*f + l15][ksel];
    }
    #pragma unroll
    for (int fm=0; fm<4; fm++)
      #pragma unroll
      for (int fn=0; fn<4; fn++)
        acc[fm][fn] = MFMA16(a[fm], b[fn], acc[fm][fn], 0,0,0);
  }
  int rowoff = (lane>>4)*4;
  #pragma unroll
  for (int fm=0; fm<4; fm++)
    #pragma unroll
    for (int fn=0; fn<4; fn++)
      #pragma unroll
      for (int e=0; e<4; e++){
        size_t idx = (size_t)(m0+wr+16*fm+rowoff+e)*N + n0+wc+16*fn+l15;
        float v = acc[fm][fn][e];
        if (out_bf) ((u16*)Cout)[idx] = f2bf(v);
        else ((float*)Cout)[idx] = v;
      }
}

// ------------- small projections x@Wbeta, x@Wg -> [T][8] each -------------
__global__ void proj_small(const float* __restrict__ x, const float* __restrict__ Wb, const float* __restrict__ Wg,
                           float* __restrict__ xWb, float* __restrict__ xWg){
  int w = threadIdx.x>>6, lane = threadIdx.x&63;
  int t = blockIdx.x*4 + w;
  float accB[8], accG[8];
  #pragma unroll
  for (int o=0;o<8;o++){ accB[o]=0.f; accG[o]=0.f; }
  for (int k=lane; k<DM; k+=64){
    float xv = x[(size_t)t*DM + k];
    #pragma unroll
    for (int o=0;o<8;o++){ accB[o] += xv*Wb[k*8+o]; accG[o] += xv*Wg[k*8+o]; }
  }
  #pragma unroll
  for (int o=0;o<8;o++){
    float b = accB[o], g = accG[o];
    #pragma unroll
    for (int d=1; d<64; d<<=1){ b += __shfl_xor(b, d, 64); g += __shfl_xor(g, d, 64); }
    if (lane==0){ xWb[t*8+o] = b; xWg[t*8+o] = g; }
  }
}

// ------------- beta = 2*sigmoid, g = logsigmoid, G = cumsum (per head) -------------
__global__ void scan_g(const float* __restrict__ xWb, const float* __restrict__ xWg,
                       float* __restrict__ beta, float* __restrict__ G){
  int h = threadIdx.x>>6, lane = threadIdx.x&63;
  float off = 0.f;
  for (int tile=0; tile<TLEN/64; ++tile){
    int t = tile*64 + lane;
    float braw = xWb[t*8+h];
    beta[h*TLEN+t] = 2.f/(1.f+expf(-braw));
    float graw = xWg[t*8+h];
    float g = (graw < 0.f) ? (graw - log1pf(expf(graw))) : (-log1pf(expf(-graw)));
    #pragma unroll
    for (int d=1; d<64; d<<=1){ float n = __shfl_up(g, d, 64); if (lane>=d) g += n; }
    G[h*TLEN+t] = g + off;
    off += __shfl(g, 63, 64);
  }
}

// ------------- per-(t,head) RMS norm in place -------------
__global__ void rms_inplace(float* __restrict__ buf, const float* __restrict__ wn){
  int lane = threadIdx.x;
  int t = blockIdx.x>>3, h = blockIdx.x&7;
  size_t base = (size_t)t*DM + h*HD;
  float v0 = buf[base+lane], v1 = buf[base+64+lane];
  float ss = v0*v0 + v1*v1;
  #pragma unroll
  for (int d=1; d<64; d<<=1) ss += __shfl_xor(ss, d, 64);
  float f = rsqrtf(ss*(1.f/128.f) + 1e-6f);
  buf[base+lane] = v0*f*wn[lane];
  buf[base+64+lane] = v1*f*wn[64+lane];
}

// ------------- causal depthwise conv(4) + silu + per-head l2 norm -------------
__global__ void conv_silu_norm(const float* __restrict__ wpre, const float* __restrict__ cw,
                               float* __restrict__ wd){
  int t = blockIdx.x, tid = threadIdx.x;
  int c0 = tid*4;
  float cwa[4][4];
  #pragma unroll
  for (int c=0;c<4;c++){
    float4 v = *(const float4*)&cw[(c0+c)*4];
    cwa[c][0]=v.x; cwa[c][1]=v.y; cwa[c][2]=v.z; cwa[c][3]=v.w;
  }
  float acc[4] = {0.f,0.f,0.f,0.f};
  #pragma unroll
  for (int i=0;i<4;i++){
    int ti = t-3+i;
    if (ti >= 0){
      float4 xv = *(const float4*)&wpre[(size_t)ti*DM + c0];
      acc[0] += xv.x*cwa[0][i]; acc[1] += xv.y*cwa[1][i];
      acc[2] += xv.z*cwa[2][i]; acc[3] += xv.w*cwa[3][i];
    }
  }
  float s[4], ss = 0.f;
  #pragma unroll
  for (int c=0;c<4;c++){ s[c] = acc[c]/(1.f+__expf(-acc[c])); ss += s[c]*s[c]; }
  #pragma unroll
  for (int d=1; d<32; d<<=1) ss += __shfl_xor(ss, d, 64);
  float f = rsqrtf(ss + 1e-6f);
  float4 o = {s[0]*f, s[1]*f, s[2]*f, s[3]*f};
  *(float4*)&wd[(size_t)t*DM + c0] = o;
}

// ------------- gram: per (h,chunk) four 64x64 matrices via split-bf16 MFMA -------------
// plane 0: W.W^T  plane 1: W.K^T  plane 2: Q.W^T  plane 3: Q.K^T
__global__ __launch_bounds__(256) void gram_kernel(
    const u16* __restrict__ Whi, const u16* __restrict__ Wlo,
    const u16* __restrict__ Khi, const u16* __restrict__ Klo,
    const u16* __restrict__ Qhi, const u16* __restrict__ Qlo,
    float* __restrict__ G4){
  int h = blockIdx.x>>5, I = blockIdx.x&31, t0 = I*64;
  int tid = threadIdx.x, lane = tid&63, w = tid>>6;
  int l15 = lane&15, l4 = lane>>4;
  const u16 *Ah, *Al, *Bh, *Bl;
  if (w==0){ Ah=Whi; Al=Wlo; Bh=Whi; Bl=Wlo; }
  else if (w==1){ Ah=Whi; Al=Wlo; Bh=Khi; Bl=Klo; }
  else if (w==2){ Ah=Qhi; Al=Qlo; Bh=Whi; Bl=Wlo; }
  else { Ah=Qhi; Al=Qlo; Bh=Khi; Bl=Klo; }
  size_t rowbase = (size_t)t0*DM + h*HD;
  f32x4 acc[4][4];
  #pragma unroll
  for (int a=0;a<4;a++)
    #pragma unroll
    for (int b=0;b<4;b++) acc[a][b] = (f32x4){0.f,0.f,0.f,0.f};
  #pragma unroll 1
  for (int ks=0; ks<4; ++ks){
    bf16x8 ah[4], al[4], bh[4], bl[4];
    #pragma unroll
    for (int f=0; f<4; f++){
      size_t off = rowbase + (size_t)(16*f + l15)*DM + ks*32 + l4*8;
      ah[f] = *(const bf16x8*)(Ah + off);
      al[f] = *(const bf16x8*)(Al + off);
      bh[f] = *(const bf16x8*)(Bh + off);
      bl[f] = *(const bf16x8*)(Bl + off);
    }
    #pragma unroll
    for (int fm=0; fm<4; fm++)
      #pragma unroll
      for (int fn=0; fn<4; fn++){
        acc[fm][fn] = MFMA16(ah[fm], bh[fn], acc[fm][fn], 0,0,0);
        acc[fm][fn] = MFMA16(ah[fm], bl[fn], acc[fm][fn], 0,0,0);
        acc[fm][fn] = MFMA16(al[fm], bh[fn], acc[fm][fn], 0,0,0);
      }
  }
  float* out = G4 + ((size_t)(h*32+I)*4 + w)*4096;
  #pragma unroll
  for (int fm=0; fm<4; fm++)
    #pragma unroll
    for (int fn=0; fn<4; fn++)
      #pragma unroll
      for (int e=0; e<4; e++)
        out[(16*fm + l4*4 + e)*64 + 16*fn + l15] = acc[fm][fn][e];
}

// ------------- solve: per (h,chunk) forward substitution for b_k, b_w -------------
// reads planes 0 (Sww), 1 (WK); writes beta-scaled solutions TRANSPOSED:
//   plane0 <- XkT[j][s] = beta_s*b_k[s][j]   plane1 <- XwT[s][r] = beta_r*b_w[r][s]
__global__ __launch_bounds__(128) void solve_kernel(float* __restrict__ G4, const float* __restrict__ betaB){
  int h = blockIdx.x>>5, I = blockIdx.x&31, t0 = I*64;
  int tid = threadIdx.x;
  __shared__ float M[64][68];
  __shared__ float X[64][132];
  __shared__ float bet[64];
  float* base = G4 + (size_t)(h*32+I)*4*4096;
  float* Sww = base;
  float* WK  = base + 4096;
  if (tid < 64) bet[tid] = betaB[h*TLEN + t0 + tid];
  __syncthreads();
  #pragma unroll 1
  for (int i=0;i<32;i++){
    int idx = i*128 + tid;
    int s = idx>>6, r = idx&63;
    float sww = Sww[idx];
    M[s][r] = (s>r) ? sww*bet[r] : ((s==r)?1.f:0.f);
    X[s][64+r] = (s>r) ? sww : 0.f;
    X[s][r]    = (s>r) ? WK[idx] : 0.f;
  }
  __syncthreads();
  {
    int c = tid;
    for (int s=1; s<64; ++s){
      float acc = X[s][c];
      int r = 0;
      for (; r+4<=s; r+=4)
        acc -= M[s][r]*X[r][c] + M[s][r+1]*X[r+1][c] + M[s][r+2]*X[r+2][c] + M[s][r+3]*X[r+3][c];
      for (; r<s; ++r) acc -= M[s][r]*X[r][c];
      X[s][c] = acc;
    }
    #pragma unroll 1
    for (int s=0;s<64;++s) X[s][c] *= bet[s];
  }
  __syncthreads();
  #pragma unroll 1
  for (int i=0;i<32;i++){
    int idx = i*128 + tid;
    int row = idx>>6, col = idx&63;
    Sww[idx] = X[col][row];        // XkT[j=row][s=col] = Xk[s][j] = X[s][j]
    WK[idx]  = X[col][64+row];     // XwT[s=row][r=col] = Xw[r][s] = X[r][64+s]
  }
}

// ------------- post (MFMA): per (h,chunk) A_diag, -C, Qtilde, Ktilde -------------
// P1: Adiag = QK + Dt*(-Xk)          (Dt = tril(QW), acc preloaded with QK)
// P2: mC[t][s] = -beta_s*(Dt[t][s] + (Dt*(-Xw))[t][s])   -> LDS bf16 hi/lo
// P3: Ktilde = K + (-XkT)*W^T        P4: Qtilde = Q + mC*W^T
__global__ __launch_bounds__(256) void post_kernel(
    const float* __restrict__ G4, const float* __restrict__ Qn, const float* __restrict__ Kn,
    const u16* __restrict__ Whi, const float* __restrict__ betaB,
    float* __restrict__ Adiag, u16* __restrict__ Qt, u16* __restrict__ Ktb){
  int h = blockIdx.x>>5, I = blockIdx.x&31, t0 = I*64;
  int tid = threadIdx.x, lane = tid&63, w = tid>>6;
  int l15 = lane&15, l4 = lane>>4;
  const float* XkT = G4 + (size_t)(h*32+I)*4*4096;   // [j][s]
  const float* XwT = XkT + 4096;                      // [s][r]
  const float* QW  = XkT + 2*4096;                    // [t][s]
  const float* QK  = XkT + 3*4096;                    // [t][j]
  __shared__ u16 WT[128][72];   // W^T[d][s] bf16-hi, pitch 72 (144B, 16B-aligned, 2-way banks)
  __shared__ u16 Ch[64][72];    // -C hi
  __shared__ u16 Cl[64][72];    // -C lo

  // stage W^T: WT[d][s] = Whi[t0+s][h*HD+d]; strided global reads, contiguous LDS writes
  {
    int d = tid>>1, half = (tid&1)*32;
    u16 tmp[32];
    #pragma unroll
    for (int i=0;i<32;i++)
      tmp[i] = Whi[(size_t)(t0+half+i)*DM + h*HD + d];
    #pragma unroll
    for (int i=0;i<32;i+=8){
      U16x8 u;
      #pragma unroll
      for (int e=0;e<8;e++) u.us[e] = tmp[i+e];
      *(uint4*)&WT[d][half+i] = u.u4;
    }
  }

  // A-fragments D = tril(QW), rows (16w+l15), hi/lo, 2 k-steps
  bf16x8 Dh[2], Dl[2];
  {
    int t = 16*w + l15;
    #pragma unroll
    for (int ks=0; ks<2; ++ks){
      const float* p = QW + t*64 + ks*32 + l4*8;
      U16x8 hh, ll;
      #pragma unroll
      for (int e=0;e<8;e++){
        int s = ks*32 + l4*8 + e;
        float v = (s<=t) ? p[e] : 0.f;
        u16 hv = f2bf(v);
        hh.us[e] = hv; ll.us[e] = f2bf(v - bf2f(hv));
      }
      Dh[ks] = hh.bf; Dl[ks] = ll.bf;
    }
  }
  int mrow = 16*w + l4*4;    // acc row base; full row = mrow+e

  // ---- P1: Adiag ----
  {
    float* outp = Adiag + (size_t)(h*32+I)*64*64;
    #pragma unroll 1
    for (int fn=0; fn<4; ++fn){
      f32x4 acc;
      #pragma unroll
      for (int e=0;e<4;e++) acc[e] = QK[(mrow+e)*64 + 16*fn + l15];
      #pragma unroll
      for (int ks=0; ks<2; ++ks){
        const float* p = XkT + (16*fn+l15)*64 + ks*32 + l4*8;
        U16x8 bh, bl;
        #pragma unroll
        for (int e=0;e<8;e++){
          float v = -p[e];
          u16 hv = f2bf(v); bh.us[e]=hv; bl.us[e]=f2bf(v - bf2f(hv));
        }
        acc = MFMA16(Dh[ks], bh.bf, acc, 0,0,0);
        acc = MFMA16(Dh[ks], bl.bf, acc, 0,0,0);
        acc = MFMA16(Dl[ks], bh.bf, acc, 0,0,0);
      }
      #pragma unroll
      for (int e=0;e<4;e++) outp[(mrow+e)*64 + 16*fn + l15] = acc[e];
    }
  }
  // ---- P2: -C -> LDS hi/lo ----
  {
    #pragma unroll 1
    for (int fn=0; fn<4; ++fn){
      f32x4 acc = (f32x4){0.f,0.f,0.f,0.f};
      #pragma unroll
      for (int ks=0; ks<2; ++ks){
        const float* p = XwT + (16*fn+l15)*64 + ks*32 + l4*8;
        U16x8 bh, bl;
        #pragma unroll
        for (int e=0;e<8;e++){
          float v = -p[e];
          u16 hv = f2bf(v); bh.us[e]=hv; bl.us[e]=f2bf(v - bf2f(hv));
        }
        acc = MFMA16(Dh[ks], bh.bf, acc, 0,0,0);
        acc = MFMA16(Dh[ks], bl.bf, acc, 0,0,0);
        acc = MFMA16(Dl[ks], bh.bf, acc, 0,0,0);
      }
      int s = 16*fn + l15;
      float bet = betaB[h*TLEN + t0 + s];
      #pragma unroll
      for (int e=0;e<4;e++){
        int t = mrow + e;
        float Dts = (s<=t) ? QW[t*64+s] : 0.f;
        float mc = -bet*(Dts + acc[e]);
        u16 hv = f2bf(mc);
        Ch[t][s] = hv;
        Cl[t][s] = f2bf(mc - bf2f(hv));
      }
    }
  }
  __syncthreads();
  // ---- P3: Ktilde = K + (-XkT rows)*WT ----
  {
    bf16x8 Ah[2], Al[2];
    int j = 16*w + l15;
    #pragma unroll
    for (int ks=0; ks<2; ++ks){
      const float* p = XkT + j*64 + ks*32 + l4*8;
      U16x8 hh, ll;
      #pragma unroll
      for (int e=0;e<8;e++){
        float v = -p[e];
        u16 hv = f2bf(v); hh.us[e]=hv; ll.us[e]=f2bf(v - bf2f(hv));
      }
      Ah[ks] = hh.bf; Al[ks] = ll.bf;
    }
    f32x4 acc[8];
    #pragma unroll
    for (int fn=0; fn<8; ++fn)
      #pragma unroll
      for (int e=0;e<4;e++)
        acc[fn][e] = Kn[(size_t)(t0+mrow+e)*DM + h*HD + 16*fn + l15];
    #pragma unroll
    for (int ks=0; ks<2; ++ks)
      #pragma unroll
      for (int fn=0; fn<8; ++fn){
        bf16x8 b = *(const bf16x8*)&WT[16*fn+l15][ks*32 + l4*8];
        acc[fn] = MFMA16(Ah[ks], b, acc[fn], 0,0,0);
        acc[fn] = MFMA16(Al[ks], b, acc[fn], 0,0,0);
      }
    #pragma unroll
    for (int fn=0; fn<8; ++fn)
      #pragma unroll
      for (int e=0;e<4;e++)
        Ktb[((size_t)h*TLEN + t0+mrow+e)*HD + 16*fn + l15] = f2bf(acc[fn][e]);
  }
  // ---- P4: Qtilde = Q + mC*WT ----
  {
    bf16x8 Ah[2], Al[2];
    int t = 16*w + l15;
    #pragma unroll
    for (int ks=0; ks<2; ++ks){
      Ah[ks] = *(const bf16x8*)&Ch[t][ks*32 + l4*8];
      Al[ks] = *(const bf16x8*)&Cl[t][ks*32 + l4*8];
    }
    f32x4 acc[8];
    #pragma unroll
    for (int fn=0; fn<8; ++fn)
      #pragma unroll
      for (int e=0;e<4;e++)
        acc[fn][e] = Qn[(size_t)(t0+mrow+e)*DM + h*HD + 16*fn + l15];
    #pragma unroll
    for (int ks=0; ks<2; ++ks)
      #pragma unroll
      for (int fn=0; fn<8; ++fn){
        bf16x8 b = *(const bf16x8*)&WT[16*fn+l15][ks*32 + l4*8];
        acc[fn] = MFMA16(Ah[ks], b, acc[fn], 0,0,0);
        acc[fn] = MFMA16(Al[ks], b, acc[fn], 0,0,0);
      }
    #pragma unroll
    for (int fn=0; fn<8; ++fn)
      #pragma unroll
      for (int e=0;e<4;e++)
        Qt[((size_t)h*TLEN + t0+mrow+e)*HD + 16*fn + l15] = f2bf(acc[fn][e]);
  }
}

// ------------- fused windowed attention: per (head, chunk I) -------------
// window cols 0..63 = chunk I-1 (masked out for I==0), cols 64..127 = diag chunk I
__global__ __launch_bounds__(256) void attn_win(const u16* __restrict__ Qt, const u16* __restrict__ Ktb,
    const float* __restrict__ Adiag, const float* __restrict__ G,
    const u16* __restrict__ Vt, u16* __restrict__ obuf){
  int h = blockIdx.x>>5, I = blockIdx.x&31;
  int tid = threadIdx.x, lane = tid&63, w = tid>>6;
  int l15 = lane&15, l4 = lane>>4;
  __shared__ float S[64][136];
  __shared__ u16 P[64][136];

  // phase A: S lower half = Qtilde_I @ Ktilde_{I-1}^T via MFMA
  if (I > 0){
    f32x4 acc4[4];
    #pragma unroll
    for (int f=0;f<4;f++) acc4[f] = (f32x4){0.f,0.f,0.f,0.f};
    #pragma unroll 1
    for (int ks=0; ks<4; ++ks){
      bf16x8 af = *(const bf16x8*)(Qt + ((size_t)h*TLEN + I*64 + 16*w + l15)*HD + ks*32 + l4*8);
      #pragma unroll
      for (int fn=0; fn<4; ++fn){
        bf16x8 bf = *(const bf16x8*)(Ktb + ((size_t)h*TLEN + (I-1)*64 + 16*fn + l15)*HD + ks*32 + l4*8);
        acc4[fn] = MFMA16(af, bf, acc4[fn], 0,0,0);
      }
    }
    #pragma unroll
    for (int fn=0; fn<4; ++fn)
      #pragma unroll
      for (int e=0;e<4;e++)
        S[16*w + l4*4 + e][16*fn + l15] = acc4[fn][e];
  }
  // phase B: diag copy (and zero lower half when I==0)
  #pragma unroll 1
  for (int i=0;i<16;i++){
    int idx = i*256 + tid;
    int tq = idx>>6, j = idx&63;
    S[tq][64+j] = Adiag[((size_t)(h*32+I)*64 + tq)*64 + j];
    if (I == 0) S[tq][j] = 0.f;
  }
  __syncthreads();

  // phase C: softmax with FoX gates; 4 threads per row, 32 cols each
  {
    int r = tid>>2, qd = tid&3, c0 = qd*32;
    int t = I*64 + r;
    float Gt = G[h*TLEN + t];
    const float scale = 0.08838834764831845f;
    int base = I*64 - 64;
    float lg[32];
    float mx = -1e30f;
    #pragma unroll
    for (int e=0;e<32;e++){
      int c = c0 + e;
      int j = base + c;
      float gj = G[h*TLEN + (j<0?0:j)];
      float v = (j>=0 && j<=t) ? (S[r][c]*scale + Gt - gj) : -1e30f;
      lg[e] = v;
      mx = fmaxf(mx, v);
    }
    mx = fmaxf(mx, __shfl_xor(mx, 1, 64));
    mx = fmaxf(mx, __shfl_xor(mx, 2, 64));
    float sum = 0.f;
    #pragma unroll
    for (int e=0;e<32;e++){ float p = __expf(lg[e]-mx); lg[e] = p; sum += p; }
    sum += __shfl_xor(sum, 1, 64);
    sum += __shfl_xor(sum, 2, 64);
    float inv = 1.f/sum;
    #pragma unroll
    for (int e8=0;e8<4;e8++){
      U16x8 u;
      #pragma unroll
      for (int e=0;e<8;e++) u.us[e] = f2bf(lg[e8*8+e]*inv);
      *(uint4*)&P[r][c0 + e8*8] = u.u4;
    }
  }
  __syncthreads();

  // phase D: O = P @ V_window via MFMA
  {
    f32x4 acc[8];
    #pragma unroll
    for (int f=0;f<8;f++) acc[f] = (f32x4){0.f,0.f,0.f,0.f};
    #pragma unroll 1
    for (int ks=0; ks<4; ++ks){
      bf16x8 pa = *(const bf16x8*)&P[16*w + l15][ks*32 + l4*8];
      int jb = (I-1)*64 + ks*32 + l4*8;
      if (jb < 0) jb = 0;   // masked cols (P==0) read valid memory
      #pragma unroll
      for (int fd=0; fd<8; ++fd){
        bf16x8 vb = *(const bf16x8*)(Vt + ((size_t)(h*HD + l15 + 16*fd))*TLEN + jb);
        acc[fd] = MFMA16(pa, vb, acc[fd], 0,0,0);
      }
    }
    #pragma unroll
    for (int fd=0; fd<8; ++fd)
      #pragma unroll
      for (int e=0;e<4;e++)
        obuf[(size_t)(I*64 + 16*w + l4*4 + e)*DM + h*HD + l15 + 16*fd] = f2bf(acc[fd][e]);
  }
}

extern "C" void kernel_launch(void* const* d_in, const int* in_sizes, int n_in,
                              void* d_out, int out_size, void* d_ws, size_t ws_size,
                              hipStream_t stream){
  const float* x     = (const float*)d_in[0];
  const float* Wq    = (const float*)d_in[1];
  const float* Wk    = (const float*)d_in[2];
  const float* Wv    = (const float*)d_in[3];
  const float* Ww    = (const float*)d_in[4];
  const float* Wbeta = (const float*)d_in[5];
  const float* Wg    = (const float*)d_in[6];
  const float* Wo    = (const float*)d_in[7];
  const float* convw = (const float*)d_in[8];
  const float* qnw   = (const float*)d_in[9];
  const float* knw   = (const float*)d_in[10];

  char* ws = (char*)d_ws;
  size_t off = 0;
  auto take = [&](size_t n)->char*{ char* p = ws + off; off += (n + 255) & ~(size_t)255; return p; };

  u16*  xb    = (u16*)take((size_t)TLEN*DM*2);      // aliased later by obuf
  u16*  WqT   = (u16*)take((size_t)DM*DM*2);
  u16*  WkT   = (u16*)take((size_t)DM*DM*2);
  u16*  WvT   = (u16*)take((size_t)DM*DM*2);
  u16*  WwT   = (u16*)take((size_t)DM*DM*2);
  u16*  WoT   = (u16*)take((size_t)DM*DM*2);
  float* Qn   = (float*)take((size_t)TLEN*DM*4);
  float* Kn   = (float*)take((size_t)TLEN*DM*4);
  float* Vraw = (float*)take((size_t)TLEN*DM*4);    // aliased later by Adiag
  float* Wpre = (float*)take((size_t)TLEN*DM*4);
  float* Wdir = (float*)take((size_t)TLEN*DM*4);
  u16*  Vt    = (u16*)take((size_t)DM*TLEN*2);
  float* xWb  = (float*)take((size_t)TLEN*8*4);
  float* xWg  = (float*)take((size_t)TLEN*8*4);
  float* betaB= (float*)take((size_t)NH*TLEN*4);
  float* GB   = (float*)take((size_t)NH*TLEN*4);
  u16*  Qt    = (u16*)take((size_t)NH*TLEN*HD*2);
  u16*  Ktb   = (u16*)take((size_t)NH*TLEN*HD*2);
  u16*  Whi   = (u16*)take((size_t)TLEN*DM*2);
  u16*  Wlo   = (u16*)take((size_t)TLEN*DM*2);
  u16*  Khi   = (u16*)take((size_t)TLEN*DM*2);
  u16*  Klo   = (u16*)take((size_t)TLEN*DM*2);
  u16*  Qhi   = (u16*)take((size_t)TLEN*DM*2);
  u16*  Qlo   = (u16*)take((size_t)TLEN*DM*2);
  float* G4   = (float*)take((size_t)NH*32*4*64*64*4);   // 16 MB

  float* Adiag = (float*)Vraw;   // 4 MB needed; Vraw dead after Vt transpose
  u16*  obuf  = xb;              // 4 MB; xb dead after the 4 projection GEMMs

  cast_f32_bf16<<<dim3(TLEN*DM/(256*8)), dim3(256), 0, stream>>>(x, xb, TLEN*DM);
  transpose_cast<<<dim3(16,16), dim3(256), 0, stream>>>(Wq, WqT, DM, DM);
  transpose_cast<<<dim3(16,16), dim3(256), 0, stream>>>(Wk, WkT, DM, DM);
  transpose_cast<<<dim3(16,16), dim3(256), 0, stream>>>(Wv, WvT, DM, DM);
  transpose_cast<<<dim3(16,16), dim3(256), 0, stream>>>(Ww, WwT, DM, DM);
  transpose_cast<<<dim3(16,16), dim3(256), 0, stream>>>(Wo, WoT, DM, DM);

  gemm_bf16<<<dim3(DM/128, TLEN/128), dim3(256), 0, stream>>>(xb, WqT, Qn, TLEN, DM, DM, 0);
  gemm_bf16<<<dim3(DM/128, TLEN/128), dim3(256), 0, stream>>>(xb, WkT, Kn, TLEN, DM, DM, 0);
  gemm_bf16<<<dim3(DM/128, TLEN/128), dim3(256), 0, stream>>>(xb, WvT, Vraw, TLEN, DM, DM, 0);
  gemm_bf16<<<dim3(DM/128, TLEN/128), dim3(256), 0, stream>>>(xb, WwT, Wpre, TLEN, DM, DM, 0);

  proj_small<<<dim3(TLEN/4), dim3(256), 0, stream>>>(x, Wbeta, Wg, xWb, xWg);
  scan_g<<<dim3(1), dim3(512), 0, stream>>>(xWb, xWg, betaB, GB);

  rms_inplace<<<dim3(TLEN*NH), dim3(64), 0, stream>>>(Qn, qnw);
  rms_inplace<<<dim3(TLEN*NH), dim3(64), 0, stream>>>(Kn, knw);
  conv_silu_norm<<<dim3(TLEN), dim3(256), 0, stream>>>(Wpre, convw, Wdir);
  transpose_cast<<<dim3(16,32), dim3(256), 0, stream>>>(Vraw, Vt, TLEN, DM);   // Vraw dead after this

  precast_hilo<<<dim3(TLEN*DM/(256*8)), dim3(256), 0, stream>>>(Wdir, Whi, Wlo, TLEN*DM);
  precast_hilo<<<dim3(TLEN*DM/(256*8)), dim3(256), 0, stream>>>(Kn,   Khi, Klo, TLEN*DM);
  precast_hilo<<<dim3(TLEN*DM/(256*8)), dim3(256), 0, stream>>>(Qn,   Qhi, Qlo, TLEN*DM);

  gram_kernel<<<dim3(256), dim3(256), 0, stream>>>(Whi, Wlo, Khi, Klo, Qhi, Qlo, G4);
  solve_kernel<<<dim3(256), dim3(128), 0, stream>>>(G4, betaB);
  post_kernel<<<dim3(256), dim3(256), 0, stream>>>(G4, Qn, Kn, Whi, betaB, Adiag, Qt, Ktb);

  attn_win<<<dim3(256), dim3(256), 0, stream>>>(Qt, Ktb, Adiag, GB, Vt, obuf);

  // FINAL PROJECTION — d_out is FLOAT32 (reference output dtype), not bf16.
  gemm_bf16<<<dim3(DM/128, TLEN/128), dim3(256), 0, stream>>>(obuf, WoT, d_out, TLEN, DM, DM, 0);
}

// Round 6
// 399.614 us; speedup vs baseline: 1.1994x; 1.0704x over previous
//
#include <hip/hip_runtime.h>

#define TLEN 2048
#define DM 1024
#define NH 8
#define HD 128

typedef unsigned short u16;
typedef __bf16 bf16_t;
typedef bf16_t bf16x8 __attribute__((ext_vector_type(8)));
typedef float f32x4 __attribute__((ext_vector_type(4)));
typedef unsigned short ushort8 __attribute__((ext_vector_type(8)));

union U16x8 { uint4 u4; ushort8 us; bf16x8 bf; };

__device__ __forceinline__ u16 f2bf(float f){
  unsigned u = __float_as_uint(f);
  u += 0x7FFFu + ((u>>16)&1u);
  return (u16)(u>>16);
}
__device__ __forceinline__ float bf2f(u16 u){ return __uint_as_float(((unsigned)u)<<16); }

#define MFMA16 __builtin_amdgcn_mfma_f32_16x16x32_bf16

// ---------------- elementwise cast f32 -> bf16 ----------------
__global__ void cast_f32_bf16(const float* __restrict__ in, u16* __restrict__ out, int n){
  int i = (blockIdx.x*256 + threadIdx.x)*8;
  if (i >= n) return;
  float4 a = *(const float4*)&in[i];
  float4 b = *(const float4*)&in[i+4];
  U16x8 r;
  r.us[0]=f2bf(a.x); r.us[1]=f2bf(a.y); r.us[2]=f2bf(a.z); r.us[3]=f2bf(a.w);
  r.us[4]=f2bf(b.x); r.us[5]=f2bf(b.y); r.us[6]=f2bf(b.z); r.us[7]=f2bf(b.w);
  *(uint4*)&out[i] = r.u4;
}

// ---------------- split cast: f32 -> bf16 hi + bf16 lo ----------------
__global__ void precast_hilo(const float* __restrict__ in, u16* __restrict__ hi, u16* __restrict__ lo, int n){
  int i = (blockIdx.x*256 + threadIdx.x)*8;
  if (i >= n) return;
  float4 a = *(const float4*)&in[i];
  float4 b = *(const float4*)&in[i+4];
  float v[8] = {a.x,a.y,a.z,a.w,b.x,b.y,b.z,b.w};
  U16x8 rh, rl;
  #pragma unroll
  for (int e=0;e<8;e++){
    u16 h = f2bf(v[e]);
    rh.us[e] = h;
    rl.us[e] = f2bf(v[e] - bf2f(h));
  }
  *(uint4*)&hi[i] = rh.u4;
  *(uint4*)&lo[i] = rl.u4;
}

// ------------- transpose + cast: in f32 [R][C] -> out bf16 [C][R] -------------
__global__ void transpose_cast(const float* __restrict__ in, u16* __restrict__ out, int R, int C){
  __shared__ float t[64][65];
  int r0 = blockIdx.y*64, c0 = blockIdx.x*64;
  int tid = threadIdx.x;
  int r = tid>>2, q = tid&3;
  const float* ip = in + (size_t)(r0+r)*C + c0 + q*16;
  #pragma unroll
  for (int i=0;i<4;i++){
    float4 v = *(const float4*)(ip + i*4);
    t[r][q*16+i*4+0]=v.x; t[r][q*16+i*4+1]=v.y; t[r][q*16+i*4+2]=v.z; t[r][q*16+i*4+3]=v.w;
  }
  __syncthreads();
  int oc = tid>>2;
  U16x8 lo, hi;
  #pragma unroll
  for (int i=0;i<8;i++) lo.us[i] = f2bf(t[q*16+i][oc]);
  #pragma unroll
  for (int i=0;i<8;i++) hi.us[i] = f2bf(t[q*16+8+i][oc]);
  u16* op = out + (size_t)(c0+oc)*R + r0 + q*16;
  *(uint4*)&op[0] = lo.u4;
  *(uint4*)&op[8] = hi.u4;
}

// ------------- bf16 GEMM: A[M][K] rm, Bt[N][K] rm, C = A@B (fp32 or bf16 out) -------------
__global__ __launch_bounds__(256) void gemm_bf16(const u16* __restrict__ A, const u16* __restrict__ Bt,
                                                 void* __restrict__ Cout, int M, int N, int K, int out_bf){
  __shared__ u16 As[128][40];
  __shared__ u16 Bs[128][40];
  int tid = threadIdx.x, lane = tid&63, w = tid>>6;
  int m0 = blockIdx.y*128, n0 = blockIdx.x*128;
  int wr = (w>>1)*64, wc = (w&1)*64;
  f32x4 acc[4][4];
  #pragma unroll
  for (int a=0;a<4;a++)
    #pragma unroll
    for (int b=0;b<4;b++) acc[a][b] = (f32x4){0.f,0.f,0.f,0.f};
  int lr = tid>>1, lc = (tid&1)*16;
  const u16* Ap = A + (size_t)(m0+lr)*K + lc;
  const u16* Bp = Bt + (size_t)(n0+lr)*K + lc;
  int l15 = lane&15, ksel = (lane>>4)*8;
  for (int kk=0; kk<K; kk+=32){
    uint4 av0 = *(const uint4*)(Ap+kk); uint4 av1 = *(const uint4*)(Ap+kk+8);
    uint4 bv0 = *(const uint4*)(Bp+kk); uint4 bv1 = *(const uint4*)(Bp+kk+8);
    __syncthreads();
    *(uint4*)&As[lr][lc] = av0; *(uint4*)&As[lr][lc+8] = av1;
    *(uint4*)&Bs[lr][lc] = bv0; *(uint4*)&Bs[lr][lc+8] = bv1;
    __syncthreads();
    bf16x8 a[4], b[4];
    #pragma unroll
    for (int f=0; f<4; f++){
      a[f] = *(const bf16x8*)&As[wr + 16*f + l15][ksel];
      b[f] = *(const bf16x8*)&Bs[wc + 16*f + l15][ksel];
    }
    #pragma unroll
    for (int fm=0; fm<4; fm++)
      #pragma unroll
      for (int fn=0; fn<4; fn++)
        acc[fm][fn] = MFMA16(a[fm], b[fn], acc[fm][fn], 0,0,0);
  }
  int rowoff = (lane>>4)*4;
  #pragma unroll
  for (int fm=0; fm<4; fm++)
    #pragma unroll
    for (int fn=0; fn<4; fn++)
      #pragma unroll
      for (int e=0; e<4; e++){
        size_t idx = (size_t)(m0+wr+16*fm+rowoff+e)*N + n0+wc+16*fn+l15;
        float v = acc[fm][fn][e];
        if (out_bf) ((u16*)Cout)[idx] = f2bf(v);
        else ((float*)Cout)[idx] = v;
      }
}

// ------------- small projections x@Wbeta, x@Wg -> [T][8] each -------------
__global__ void proj_small(const float* __restrict__ x, const float* __restrict__ Wb, const float* __restrict__ Wg,
                           float* __restrict__ xWb, float* __restrict__ xWg){
  int w = threadIdx.x>>6, lane = threadIdx.x&63;
  int t = blockIdx.x*4 + w;
  float accB[8], accG[8];
  #pragma unroll
  for (int o=0;o<8;o++){ accB[o]=0.f; accG[o]=0.f; }
  for (int k=lane; k<DM; k+=64){
    float xv = x[(size_t)t*DM + k];
    #pragma unroll
    for (int o=0;o<8;o++){ accB[o] += xv*Wb[k*8+o]; accG[o] += xv*Wg[k*8+o]; }
  }
  #pragma unroll
  for (int o=0;o<8;o++){
    float b = accB[o], g = accG[o];
    #pragma unroll
    for (int d=1; d<64; d<<=1){ b += __shfl_xor(b, d, 64); g += __shfl_xor(g, d, 64); }
    if (lane==0){ xWb[t*8+o] = b; xWg[t*8+o] = g; }
  }
}

// ------------- beta = 2*sigmoid, g = logsigmoid, G = cumsum (per head) -------------
__global__ void scan_g(const float* __restrict__ xWb, const float* __restrict__ xWg,
                       float* __restrict__ beta, float* __restrict__ G){
  int h = threadIdx.x>>6, lane = threadIdx.x&63;
  float off = 0.f;
  for (int tile=0; tile<TLEN/64; ++tile){
    int t = tile*64 + lane;
    float braw = xWb[t*8+h];
    beta[h*TLEN+t] = 2.f/(1.f+expf(-braw));
    float graw = xWg[t*8+h];
    float g = (graw < 0.f) ? (graw - log1pf(expf(graw))) : (-log1pf(expf(-graw)));
    #pragma unroll
    for (int d=1; d<64; d<<=1){ float n = __shfl_up(g, d, 64); if (lane>=d) g += n; }
    G[h*TLEN+t] = g + off;
    off += __shfl(g, 63, 64);
  }
}

// ------------- per-(t,head) RMS norm in place -------------
__global__ void rms_inplace(float* __restrict__ buf, const float* __restrict__ wn){
  int lane = threadIdx.x;
  int t = blockIdx.x>>3, h = blockIdx.x&7;
  size_t base = (size_t)t*DM + h*HD;
  float v0 = buf[base+lane], v1 = buf[base+64+lane];
  float ss = v0*v0 + v1*v1;
  #pragma unroll
  for (int d=1; d<64; d<<=1) ss += __shfl_xor(ss, d, 64);
  float f = rsqrtf(ss*(1.f/128.f) + 1e-6f);
  buf[base+lane] = v0*f*wn[lane];
  buf[base+64+lane] = v1*f*wn[64+lane];
}

// ------------- causal depthwise conv(4) + silu + per-head l2 norm -------------
__global__ void conv_silu_norm(const float* __restrict__ wpre, const float* __restrict__ cw,
                               float* __restrict__ wd){
  int t = blockIdx.x, tid = threadIdx.x;
  int c0 = tid*4;
  float cwa[4][4];
  #pragma unroll
  for (int c=0;c<4;c++){
    float4 v = *(const float4*)&cw[(c0+c)*4];
    cwa[c][0]=v.x; cwa[c][1]=v.y; cwa[c][2]=v.z; cwa[c][3]=v.w;
  }
  float acc[4] = {0.f,0.f,0.f,0.f};
  #pragma unroll
  for (int i=0;i<4;i++){
    int ti = t-3+i;
    if (ti >= 0){
      float4 xv = *(const float4*)&wpre[(size_t)ti*DM + c0];
      acc[0] += xv.x*cwa[0][i]; acc[1] += xv.y*cwa[1][i];
      acc[2] += xv.z*cwa[2][i]; acc[3] += xv.w*cwa[3][i];
    }
  }
  float s[4], ss = 0.f;
  #pragma unroll
  for (int c=0;c<4;c++){ s[c] = acc[c]/(1.f+__expf(-acc[c])); ss += s[c]*s[c]; }
  #pragma unroll
  for (int d=1; d<32; d<<=1) ss += __shfl_xor(ss, d, 64);
  float f = rsqrtf(ss + 1e-6f);
  float4 o = {s[0]*f, s[1]*f, s[2]*f, s[3]*f};
  *(float4*)&wd[(size_t)t*DM + c0] = o;
}

// ------------- gram: per (h,chunk) four 64x64 matrices via split-bf16 MFMA -------------
// plane 0: W.W^T  plane 1: W.K^T  plane 2: Q.W^T  plane 3: Q.K^T
__global__ __launch_bounds__(256) void gram_kernel(
    const u16* __restrict__ Whi, const u16* __restrict__ Wlo,
    const u16* __restrict__ Khi, const u16* __restrict__ Klo,
    const u16* __restrict__ Qhi, const u16* __restrict__ Qlo,
    float* __restrict__ G4){
  int h = blockIdx.x>>5, I = blockIdx.x&31, t0 = I*64;
  int tid = threadIdx.x, lane = tid&63, w = tid>>6;
  int l15 = lane&15, l4 = lane>>4;
  const u16 *Ah, *Al, *Bh, *Bl;
  if (w==0){ Ah=Whi; Al=Wlo; Bh=Whi; Bl=Wlo; }
  else if (w==1){ Ah=Whi; Al=Wlo; Bh=Khi; Bl=Klo; }
  else if (w==2){ Ah=Qhi; Al=Qlo; Bh=Whi; Bl=Wlo; }
  else { Ah=Qhi; Al=Qlo; Bh=Khi; Bl=Klo; }
  size_t rowbase = (size_t)t0*DM + h*HD;
  f32x4 acc[4][4];
  #pragma unroll
  for (int a=0;a<4;a++)
    #pragma unroll
    for (int b=0;b<4;b++) acc[a][b] = (f32x4){0.f,0.f,0.f,0.f};
  #pragma unroll 1
  for (int ks=0; ks<4; ++ks){
    bf16x8 ah[4], al[4], bh[4], bl[4];
    #pragma unroll
    for (int f=0; f<4; f++){
      size_t off = rowbase + (size_t)(16*f + l15)*DM + ks*32 + l4*8;
      ah[f] = *(const bf16x8*)(Ah + off);
      al[f] = *(const bf16x8*)(Al + off);
      bh[f] = *(const bf16x8*)(Bh + off);
      bl[f] = *(const bf16x8*)(Bl + off);
    }
    #pragma unroll
    for (int fm=0; fm<4; fm++)
      #pragma unroll
      for (int fn=0; fn<4; fn++){
        acc[fm][fn] = MFMA16(ah[fm], bh[fn], acc[fm][fn], 0,0,0);
        acc[fm][fn] = MFMA16(ah[fm], bl[fn], acc[fm][fn], 0,0,0);
        acc[fm][fn] = MFMA16(al[fm], bh[fn], acc[fm][fn], 0,0,0);
      }
  }
  float* out = G4 + ((size_t)(h*32+I)*4 + w)*4096;
  #pragma unroll
  for (int fm=0; fm<4; fm++)
    #pragma unroll
    for (int fn=0; fn<4; fn++)
      #pragma unroll
      for (int e=0; e<4; e++)
        out[(16*fm + l4*4 + e)*64 + 16*fn + l15] = acc[fm][fn][e];
}

// ------------- solve: per (h,chunk) forward substitution for b_k, b_w -------------
// Register-resident columns: thread c<64 solves rhs_k col c (from plane1=WK),
// thread c>=64 solves rhs_w col c-64 (from plane0=Sww). Fully unrolled so the
// column array stays in VGPRs (no LDS X). Writes beta-scaled results:
//   plane0[j][s] = Xk[s][j]   (thread j, contiguous row)
//   plane1[r][s] = Xw[s][r]   (thread 64+r, contiguous row)
__global__ __launch_bounds__(128) void solve_kernel(float* __restrict__ G4, const float* __restrict__ betaB){
  int h = blockIdx.x>>5, I = blockIdx.x&31, t0 = I*64;
  int tid = threadIdx.x;
  __shared__ float M[64][68];
  __shared__ float bet[64];
  float* base = G4 + (size_t)(h*32+I)*4*4096;
  float* Sww = base;
  float* WK  = base + 4096;
  if (tid < 64) bet[tid] = betaB[h*TLEN + t0 + tid];
  __syncthreads();
  // build strictly-lower M[s][r] = Sww[s][r]*beta_r in LDS (broadcast-read later)
  #pragma unroll 1
  for (int i=0;i<32;i++){
    int idx = i*128 + tid;
    int s = idx>>6, r = idx&63;
    M[s][r] = (s>r) ? Sww[idx]*bet[r] : 0.f;
  }
  __syncthreads();
  // load RHS column into registers (masked strictly-lower)
  int col = tid & 63;
  const float* src = (tid < 64) ? WK : Sww;
  float x[64];
  #pragma unroll
  for (int s=0;s<64;++s){
    float v = src[s*64 + col];
    x[s] = (s > col) ? v : 0.f;
  }
  __syncthreads();   // all plane reads done before anyone overwrites
  // forward substitution, fully unrolled, x[] in VGPRs, M broadcast from LDS
  #pragma unroll
  for (int s=1; s<64; ++s){
    float a0=0.f, a1=0.f, a2=0.f, a3=0.f;
    #pragma unroll
    for (int r=0; r<(s&~3); r+=4){
      a0 += M[s][r  ]*x[r  ];
      a1 += M[s][r+1]*x[r+1];
      a2 += M[s][r+2]*x[r+2];
      a3 += M[s][r+3]*x[r+3];
    }
    #pragma unroll
    for (int r=(s&~3); r<s; ++r) a0 += M[s][r]*x[r];
    x[s] -= (a0+a1)+(a2+a3);
  }
  #pragma unroll
  for (int s=0;s<64;++s) x[s] *= bet[s];
  // write back: contiguous 64-float row per thread
  float* out = (tid < 64 ? Sww : WK) + (size_t)col*64;
  #pragma unroll
  for (int s=0;s<64;s+=4){
    float4 o = {x[s], x[s+1], x[s+2], x[s+3]};
    *(float4*)&out[s] = o;
  }
}

// ------------- post (MFMA): per (h,chunk) A_diag, -C, Qtilde, Ktilde -------------
// P1: Adiag = QK + Dt*(-Xk)          (Dt = tril(QW), acc preloaded with QK)
// P2: mC[t][s] = -beta_s*(Dt[t][s] + (Dt*(-Xw))[t][s])   -> LDS bf16 hi/lo
// P3: Ktilde = K + (-XkT)*W^T        P4: Qtilde = Q + mC*W^T
__global__ __launch_bounds__(256) void post_kernel(
    const float* __restrict__ G4, const float* __restrict__ Qn, const float* __restrict__ Kn,
    const u16* __restrict__ Whi, const float* __restrict__ betaB,
    float* __restrict__ Adiag, u16* __restrict__ Qt, u16* __restrict__ Ktb){
  int h = blockIdx.x>>5, I = blockIdx.x&31, t0 = I*64;
  int tid = threadIdx.x, lane = tid&63, w = tid>>6;
  int l15 = lane&15, l4 = lane>>4;
  const float* XkT = G4 + (size_t)(h*32+I)*4*4096;   // [j][s]
  const float* XwT = XkT + 4096;                      // [s][r]
  const float* QW  = XkT + 2*4096;                    // [t][s]
  const float* QK  = XkT + 3*4096;                    // [t][j]
  __shared__ u16 WT[128][72];   // W^T[d][s] bf16-hi, pitch 72 (144B, 16B-aligned, 2-way banks)
  __shared__ u16 Ch[64][72];    // -C hi
  __shared__ u16 Cl[64][72];    // -C lo

  // stage W^T: WT[d][s] = Whi[t0+s][h*HD+d]; strided global reads, contiguous LDS writes
  {
    int d = tid>>1, half = (tid&1)*32;
    u16 tmp[32];
    #pragma unroll
    for (int i=0;i<32;i++)
      tmp[i] = Whi[(size_t)(t0+half+i)*DM + h*HD + d];
    #pragma unroll
    for (int i=0;i<32;i+=8){
      U16x8 u;
      #pragma unroll
      for (int e=0;e<8;e++) u.us[e] = tmp[i+e];
      *(uint4*)&WT[d][half+i] = u.u4;
    }
  }

  // A-fragments D = tril(QW), rows (16w+l15), hi/lo, 2 k-steps
  bf16x8 Dh[2], Dl[2];
  {
    int t = 16*w + l15;
    #pragma unroll
    for (int ks=0; ks<2; ++ks){
      const float* p = QW + t*64 + ks*32 + l4*8;
      U16x8 hh, ll;
      #pragma unroll
      for (int e=0;e<8;e++){
        int s = ks*32 + l4*8 + e;
        float v = (s<=t) ? p[e] : 0.f;
        u16 hv = f2bf(v);
        hh.us[e] = hv; ll.us[e] = f2bf(v - bf2f(hv));
      }
      Dh[ks] = hh.bf; Dl[ks] = ll.bf;
    }
  }
  int mrow = 16*w + l4*4;    // acc row base; full row = mrow+e

  // ---- P1: Adiag ----
  {
    float* outp = Adiag + (size_t)(h*32+I)*64*64;
    #pragma unroll 1
    for (int fn=0; fn<4; ++fn){
      f32x4 acc;
      #pragma unroll
      for (int e=0;e<4;e++) acc[e] = QK[(mrow+e)*64 + 16*fn + l15];
      #pragma unroll
      for (int ks=0; ks<2; ++ks){
        const float* p = XkT + (16*fn+l15)*64 + ks*32 + l4*8;
        U16x8 bh, bl;
        #pragma unroll
        for (int e=0;e<8;e++){
          float v = -p[e];
          u16 hv = f2bf(v); bh.us[e]=hv; bl.us[e]=f2bf(v - bf2f(hv));
        }
        acc = MFMA16(Dh[ks], bh.bf, acc, 0,0,0);
        acc = MFMA16(Dh[ks], bl.bf, acc, 0,0,0);
        acc = MFMA16(Dl[ks], bh.bf, acc, 0,0,0);
      }
      #pragma unroll
      for (int e=0;e<4;e++) outp[(mrow+e)*64 + 16*fn + l15] = acc[e];
    }
  }
  // ---- P2: -C -> LDS hi/lo ----
  {
    #pragma unroll 1
    for (int fn=0; fn<4; ++fn){
      f32x4 acc = (f32x4){0.f,0.f,0.f,0.f};
      #pragma unroll
      for (int ks=0; ks<2; ++ks){
        const float* p = XwT + (16*fn+l15)*64 + ks*32 + l4*8;
        U16x8 bh, bl;
        #pragma unroll
        for (int e=0;e<8;e++){
          float v = -p[e];
          u16 hv = f2bf(v); bh.us[e]=hv; bl.us[e]=f2bf(v - bf2f(hv));
        }
        acc = MFMA16(Dh[ks], bh.bf, acc, 0,0,0);
        acc = MFMA16(Dh[ks], bl.bf, acc, 0,0,0);
        acc = MFMA16(Dl[ks], bh.bf, acc, 0,0,0);
      }
      int s = 16*fn + l15;
      float bet = betaB[h*TLEN + t0 + s];
      #pragma unroll
      for (int e=0;e<4;e++){
        int t = mrow + e;
        float Dts = (s<=t) ? QW[t*64+s] : 0.f;
        float mc = -bet*(Dts + acc[e]);
        u16 hv = f2bf(mc);
        Ch[t][s] = hv;
        Cl[t][s] = f2bf(mc - bf2f(hv));
      }
    }
  }
  __syncthreads();
  // ---- P3: Ktilde = K + (-XkT rows)*WT ----
  {
    bf16x8 Ah[2], Al[2];
    int j = 16*w + l15;
    #pragma unroll
    for (int ks=0; ks<2; ++ks){
      const float* p = XkT + j*64 + ks*32 + l4*8;
      U16x8 hh, ll;
      #pragma unroll
      for (int e=0;e<8;e++){
        float v = -p[e];
        u16 hv = f2bf(v); hh.us[e]=hv; ll.us[e]=f2bf(v - bf2f(hv));
      }
      Ah[ks] = hh.bf; Al[ks] = ll.bf;
    }
    f32x4 acc[8];
    #pragma unroll
    for (int fn=0; fn<8; ++fn)
      #pragma unroll
      for (int e=0;e<4;e++)
        acc[fn][e] = Kn[(size_t)(t0+mrow+e)*DM + h*HD + 16*fn + l15];
    #pragma unroll
    for (int ks=0; ks<2; ++ks)
      #pragma unroll
      for (int fn=0; fn<8; ++fn){
        bf16x8 b = *(const bf16x8*)&WT[16*fn+l15][ks*32 + l4*8];
        acc[fn] = MFMA16(Ah[ks], b, acc[fn], 0,0,0);
        acc[fn] = MFMA16(Al[ks], b, acc[fn], 0,0,0);
      }
    #pragma unroll
    for (int fn=0; fn<8; ++fn)
      #pragma unroll
      for (int e=0;e<4;e++)
        Ktb[((size_t)h*TLEN + t0+mrow+e)*HD + 16*fn + l15] = f2bf(acc[fn][e]);
  }
  // ---- P4: Qtilde = Q + mC*WT ----
  {
    bf16x8 Ah[2], Al[2];
    int t = 16*w + l15;
    #pragma unroll
    for (int ks=0; ks<2; ++ks){
      Ah[ks] = *(const bf16x8*)&Ch[t][ks*32 + l4*8];
      Al[ks] = *(const bf16x8*)&Cl[t][ks*32 + l4*8];
    }
    f32x4 acc[8];
    #pragma unroll
    for (int fn=0; fn<8; ++fn)
      #pragma unroll
      for (int e=0;e<4;e++)
        acc[fn][e] = Qn[(size_t)(t0+mrow+e)*DM + h*HD + 16*fn + l15];
    #pragma unroll
    for (int ks=0; ks<2; ++ks)
      #pragma unroll
      for (int fn=0; fn<8; ++fn){
        bf16x8 b = *(const bf16x8*)&WT[16*fn+l15][ks*32 + l4*8];
        acc[fn] = MFMA16(Ah[ks], b, acc[fn], 0,0,0);
        acc[fn] = MFMA16(Al[ks], b, acc[fn], 0,0,0);
      }
    #pragma unroll
    for (int fn=0; fn<8; ++fn)
      #pragma unroll
      for (int e=0;e<4;e++)
        Qt[((size_t)h*TLEN + t0+mrow+e)*HD + 16*fn + l15] = f2bf(acc[fn][e]);
  }
}

// ------------- fused windowed attention: per (head, chunk I) -------------
// window cols 0..63 = chunk I-1 (masked out for I==0), cols 64..127 = diag chunk I
__global__ __launch_bounds__(256) void attn_win(const u16* __restrict__ Qt, const u16* __restrict__ Ktb,
    const float* __restrict__ Adiag, const float* __restrict__ G,
    const u16* __restrict__ Vt, u16* __restrict__ obuf){
  int h = blockIdx.x>>5, I = blockIdx.x&31;
  int tid = threadIdx.x, lane = tid&63, w = tid>>6;
  int l15 = lane&15, l4 = lane>>4;
  __shared__ float S[64][136];
  __shared__ u16 P[64][136];

  // phase A: S lower half = Qtilde_I @ Ktilde_{I-1}^T via MFMA
  if (I > 0){
    f32x4 acc4[4];
    #pragma unroll
    for (int f=0;f<4;f++) acc4[f] = (f32x4){0.f,0.f,0.f,0.f};
    #pragma unroll 1
    for (int ks=0; ks<4; ++ks){
      bf16x8 af = *(const bf16x8*)(Qt + ((size_t)h*TLEN + I*64 + 16*w + l15)*HD + ks*32 + l4*8);
      #pragma unroll
      for (int fn=0; fn<4; ++fn){
        bf16x8 bf = *(const bf16x8*)(Ktb + ((size_t)h*TLEN + (I-1)*64 + 16*fn + l15)*HD + ks*32 + l4*8);
        acc4[fn] = MFMA16(af, bf, acc4[fn], 0,0,0);
      }
    }
    #pragma unroll
    for (int fn=0; fn<4; ++fn)
      #pragma unroll
      for (int e=0;e<4;e++)
        S[16*w + l4*4 + e][16*fn + l15] = acc4[fn][e];
  }
  // phase B: diag copy (and zero lower half when I==0)
  #pragma unroll 1
  for (int i=0;i<16;i++){
    int idx = i*256 + tid;
    int tq = idx>>6, j = idx&63;
    S[tq][64+j] = Adiag[((size_t)(h*32+I)*64 + tq)*64 + j];
    if (I == 0) S[tq][j] = 0.f;
  }
  __syncthreads();

  // phase C: softmax with FoX gates; 4 threads per row, 32 cols each
  {
    int r = tid>>2, qd = tid&3, c0 = qd*32;
    int t = I*64 + r;
    float Gt = G[h*TLEN + t];
    const float scale = 0.08838834764831845f;
    int base = I*64 - 64;
    float lg[32];
    float mx = -1e30f;
    #pragma unroll
    for (int e=0;e<32;e++){
      int c = c0 + e;
      int j = base + c;
      float gj = G[h*TLEN + (j<0?0:j)];
      float v = (j>=0 && j<=t) ? (S[r][c]*scale + Gt - gj) : -1e30f;
      lg[e] = v;
      mx = fmaxf(mx, v);
    }
    mx = fmaxf(mx, __shfl_xor(mx, 1, 64));
    mx = fmaxf(mx, __shfl_xor(mx, 2, 64));
    float sum = 0.f;
    #pragma unroll
    for (int e=0;e<32;e++){ float p = __expf(lg[e]-mx); lg[e] = p; sum += p; }
    sum += __shfl_xor(sum, 1, 64);
    sum += __shfl_xor(sum, 2, 64);
    float inv = 1.f/sum;
    #pragma unroll
    for (int e8=0;e8<4;e8++){
      U16x8 u;
      #pragma unroll
      for (int e=0;e<8;e++) u.us[e] = f2bf(lg[e8*8+e]*inv);
      *(uint4*)&P[r][c0 + e8*8] = u.u4;
    }
  }
  __syncthreads();

  // phase D: O = P @ V_window via MFMA
  {
    f32x4 acc[8];
    #pragma unroll
    for (int f=0;f<8;f++) acc[f] = (f32x4){0.f,0.f,0.f,0.f};
    #pragma unroll 1
    for (int ks=0; ks<4; ++ks){
      bf16x8 pa = *(const bf16x8*)&P[16*w + l15][ks*32 + l4*8];
      int jb = (I-1)*64 + ks*32 + l4*8;
      if (jb < 0) jb = 0;   // masked cols (P==0) read valid memory
      #pragma unroll
      for (int fd=0; fd<8; ++fd){
        bf16x8 vb = *(const bf16x8*)(Vt + ((size_t)(h*HD + l15 + 16*fd))*TLEN + jb);
        acc[fd] = MFMA16(pa, vb, acc[fd], 0,0,0);
      }
    }
    #pragma unroll
    for (int fd=0; fd<8; ++fd)
      #pragma unroll
      for (int e=0;e<4;e++)
        obuf[(size_t)(I*64 + 16*w + l4*4 + e)*DM + h*HD + l15 + 16*fd] = f2bf(acc[fd][e]);
  }
}

extern "C" void kernel_launch(void* const* d_in, const int* in_sizes, int n_in,
                              void* d_out, int out_size, void* d_ws, size_t ws_size,
                              hipStream_t stream){
  const float* x     = (const float*)d_in[0];
  const float* Wq    = (const float*)d_in[1];
  const float* Wk    = (const float*)d_in[2];
  const float* Wv    = (const float*)d_in[3];
  const float* Ww    = (const float*)d_in[4];
  const float* Wbeta = (const float*)d_in[5];
  const float* Wg    = (const float*)d_in[6];
  const float* Wo    = (const float*)d_in[7];
  const float* convw = (const float*)d_in[8];
  const float* qnw   = (const float*)d_in[9];
  const float* knw   = (const float*)d_in[10];

  char* ws = (char*)d_ws;
  size_t off = 0;
  auto take = [&](size_t n)->char*{ char* p = ws + off; off += (n + 255) & ~(size_t)255; return p; };

  u16*  xb    = (u16*)take((size_t)TLEN*DM*2);      // aliased later by obuf
  u16*  WqT   = (u16*)take((size_t)DM*DM*2);
  u16*  WkT   = (u16*)take((size_t)DM*DM*2);
  u16*  WvT   = (u16*)take((size_t)DM*DM*2);
  u16*  WwT   = (u16*)take((size_t)DM*DM*2);
  u16*  WoT   = (u16*)take((size_t)DM*DM*2);
  float* Qn   = (float*)take((size_t)TLEN*DM*4);
  float* Kn   = (float*)take((size_t)TLEN*DM*4);
  float* Vraw = (float*)take((size_t)TLEN*DM*4);    // aliased later by Adiag
  float* Wpre = (float*)take((size_t)TLEN*DM*4);
  float* Wdir = (float*)take((size_t)TLEN*DM*4);
  u16*  Vt    = (u16*)take((size_t)DM*TLEN*2);
  float* xWb  = (float*)take((size_t)TLEN*8*4);
  float* xWg  = (float*)take((size_t)TLEN*8*4);
  float* betaB= (float*)take((size_t)NH*TLEN*4);
  float* GB   = (float*)take((size_t)NH*TLEN*4);
  u16*  Qt    = (u16*)take((size_t)NH*TLEN*HD*2);
  u16*  Ktb   = (u16*)take((size_t)NH*TLEN*HD*2);
  u16*  Whi   = (u16*)take((size_t)TLEN*DM*2);
  u16*  Wlo   = (u16*)take((size_t)TLEN*DM*2);
  u16*  Khi   = (u16*)take((size_t)TLEN*DM*2);
  u16*  Klo   = (u16*)take((size_t)TLEN*DM*2);
  u16*  Qhi   = (u16*)take((size_t)TLEN*DM*2);
  u16*  Qlo   = (u16*)take((size_t)TLEN*DM*2);
  float* G4   = (float*)take((size_t)NH*32*4*64*64*4);   // 16 MB

  float* Adiag = (float*)Vraw;   // 4 MB needed; Vraw dead after Vt transpose
  u16*  obuf  = xb;              // 4 MB; xb dead after the 4 projection GEMMs

  cast_f32_bf16<<<dim3(TLEN*DM/(256*8)), dim3(256), 0, stream>>>(x, xb, TLEN*DM);
  transpose_cast<<<dim3(16,16), dim3(256), 0, stream>>>(Wq, WqT, DM, DM);
  transpose_cast<<<dim3(16,16), dim3(256), 0, stream>>>(Wk, WkT, DM, DM);
  transpose_cast<<<dim3(16,16), dim3(256), 0, stream>>>(Wv, WvT, DM, DM);
  transpose_cast<<<dim3(16,16), dim3(256), 0, stream>>>(Ww, WwT, DM, DM);
  transpose_cast<<<dim3(16,16), dim3(256), 0, stream>>>(Wo, WoT, DM, DM);

  gemm_bf16<<<dim3(DM/128, TLEN/128), dim3(256), 0, stream>>>(xb, WqT, Qn, TLEN, DM, DM, 0);
  gemm_bf16<<<dim3(DM/128, TLEN/128), dim3(256), 0, stream>>>(xb, WkT, Kn, TLEN, DM, DM, 0);
  gemm_bf16<<<dim3(DM/128, TLEN/128), dim3(256), 0, stream>>>(xb, WvT, Vraw, TLEN, DM, DM, 0);
  gemm_bf16<<<dim3(DM/128, TLEN/128), dim3(256), 0, stream>>>(xb, WwT, Wpre, TLEN, DM, DM, 0);

  proj_small<<<dim3(TLEN/4), dim3(256), 0, stream>>>(x, Wbeta, Wg, xWb, xWg);
  scan_g<<<dim3(1), dim3(512), 0, stream>>>(xWb, xWg, betaB, GB);

  rms_inplace<<<dim3(TLEN*NH), dim3(64), 0, stream>>>(Qn, qnw);
  rms_inplace<<<dim3(TLEN*NH), dim3(64), 0, stream>>>(Kn, knw);
  conv_silu_norm<<<dim3(TLEN), dim3(256), 0, stream>>>(Wpre, convw, Wdir);
  transpose_cast<<<dim3(16,32), dim3(256), 0, stream>>>(Vraw, Vt, TLEN, DM);   // Vraw dead after this

  precast_hilo<<<dim3(TLEN*DM/(256*8)), dim3(256), 0, stream>>>(Wdir, Whi, Wlo, TLEN*DM);
  precast_hilo<<<dim3(TLEN*DM/(256*8)), dim3(256), 0, stream>>>(Kn,   Khi, Klo, TLEN*DM);
  precast_hilo<<<dim3(TLEN*DM/(256*8)), dim3(256), 0, stream>>>(Qn,   Qhi, Qlo, TLEN*DM);

  gram_kernel<<<dim3(256), dim3(256), 0, stream>>>(Whi, Wlo, Khi, Klo, Qhi, Qlo, G4);
  solve_kernel<<<dim3(256), dim3(128), 0, stream>>>(G4, betaB);
  post_kernel<<<dim3(256), dim3(256), 0, stream>>>(G4, Qn, Kn, Whi, betaB, Adiag, Qt, Ktb);

  attn_win<<<dim3(256), dim3(256), 0, stream>>>(Qt, Ktb, Adiag, GB, Vt, obuf);

  // FINAL PROJECTION — d_out is FLOAT32 (reference output dtype), not bf16.
  gemm_bf16<<<dim3(DM/128, TLEN/128), dim3(256), 0, stream>>>(obuf, WoT, d_out, TLEN, DM, DM, 0);
}

// Round 7
// 309.320 us; speedup vs baseline: 1.5495x; 1.2919x over previous
//
#include <hip/hip_runtime.h>

#define TLEN 2048
#define DM 1024
#define NH 8
#define HD 128

typedef unsigned short u16;
typedef __bf16 bf16_t;
typedef bf16_t bf16x8 __attribute__((ext_vector_type(8)));
typedef float f32x4 __attribute__((ext_vector_type(4)));
typedef unsigned short ushort8 __attribute__((ext_vector_type(8)));

union U16x8 { uint4 u4; ushort8 us; bf16x8 bf; };

__device__ __forceinline__ u16 f2bf(float f){
  unsigned u = __float_as_uint(f);
  u += 0x7FFFu + ((u>>16)&1u);
  return (u16)(u>>16);
}
__device__ __forceinline__ float bf2f(u16 u){ return __uint_as_float(((unsigned)u)<<16); }

#define MFMA16 __builtin_amdgcn_mfma_f32_16x16x32_bf16

// async global->LDS, 16B per lane; lds dst must be wave-uniform base (HW adds lane*16)
__device__ __forceinline__ void gld16(const u16* g, u16* l){
  __builtin_amdgcn_global_load_lds((const __attribute__((address_space(1))) unsigned*)g,
                                   (__attribute__((address_space(3))) unsigned*)l, 16, 0, 0);
}

// ---------------- elementwise cast f32 -> bf16 ----------------
__global__ void cast_f32_bf16(const float* __restrict__ in, u16* __restrict__ out, int n){
  int i = (blockIdx.x*256 + threadIdx.x)*8;
  if (i >= n) return;
  float4 a = *(const float4*)&in[i];
  float4 b = *(const float4*)&in[i+4];
  U16x8 r;
  r.us[0]=f2bf(a.x); r.us[1]=f2bf(a.y); r.us[2]=f2bf(a.z); r.us[3]=f2bf(a.w);
  r.us[4]=f2bf(b.x); r.us[5]=f2bf(b.y); r.us[6]=f2bf(b.z); r.us[7]=f2bf(b.w);
  *(uint4*)&out[i] = r.u4;
}

// ---------------- split cast: f32 -> bf16 hi + bf16 lo ----------------
__global__ void precast_hilo(const float* __restrict__ in, u16* __restrict__ hi, u16* __restrict__ lo, int n){
  int i = (blockIdx.x*256 + threadIdx.x)*8;
  if (i >= n) return;
  float4 a = *(const float4*)&in[i];
  float4 b = *(const float4*)&in[i+4];
  float v[8] = {a.x,a.y,a.z,a.w,b.x,b.y,b.z,b.w};
  U16x8 rh, rl;
  #pragma unroll
  for (int e=0;e<8;e++){
    u16 h = f2bf(v[e]);
    rh.us[e] = h;
    rl.us[e] = f2bf(v[e] - bf2f(h));
  }
  *(uint4*)&hi[i] = rh.u4;
  *(uint4*)&lo[i] = rl.u4;
}

// ------------- transpose + cast: in f32 [R][C] -> out bf16 [C][R] -------------
__global__ void transpose_cast(const float* __restrict__ in, u16* __restrict__ out, int R, int C){
  __shared__ float t[64][65];
  int r0 = blockIdx.y*64, c0 = blockIdx.x*64;
  int tid = threadIdx.x;
  int r = tid>>2, q = tid&3;
  const float* ip = in + (size_t)(r0+r)*C + c0 + q*16;
  #pragma unroll
  for (int i=0;i<4;i++){
    float4 v = *(const float4*)(ip + i*4);
    t[r][q*16+i*4+0]=v.x; t[r][q*16+i*4+1]=v.y; t[r][q*16+i*4+2]=v.z; t[r][q*16+i*4+3]=v.w;
  }
  __syncthreads();
  int oc = tid>>2;
  U16x8 lo, hi;
  #pragma unroll
  for (int i=0;i<8;i++) lo.us[i] = f2bf(t[q*16+i][oc]);
  #pragma unroll
  for (int i=0;i<8;i++) hi.us[i] = f2bf(t[q*16+8+i][oc]);
  u16* op = out + (size_t)(c0+oc)*R + r0 + q*16;
  *(uint4*)&op[0] = lo.u4;
  *(uint4*)&op[8] = hi.u4;
}

// ------------- batched bf16 GEMM (m97-style global_load_lds staging) -------------
// A[TLEN][DM] bf16, up to 4 Bt[DM][DM] bf16 (row = output col), C f32 [TLEN][DM].
// grid: x = 8 * nB (bsel = x>>3), y = 16.  BK=32, tile 128x128, 4 waves.
__global__ __launch_bounds__(256) void gemm4(const u16* __restrict__ A,
    const u16* __restrict__ B0, const u16* __restrict__ B1,
    const u16* __restrict__ B2, const u16* __restrict__ B3,
    float* __restrict__ C0, float* __restrict__ C1,
    float* __restrict__ C2, float* __restrict__ C3){
  __shared__ u16 As[128*32];
  __shared__ u16 Bs[128*32];
  int tid = threadIdx.x, lane = tid&63, w = tid>>6;
  int bsel = blockIdx.x>>3;
  const u16* Bt = (bsel==0)?B0 : (bsel==1)?B1 : (bsel==2)?B2 : B3;
  float* Cout   = (bsel==0)?C0 : (bsel==1)?C1 : (bsel==2)?C2 : C3;
  int m0 = blockIdx.y*128, n0 = (blockIdx.x&7)*128;
  int wr = (w>>1)*64, wc = (w&1)*64;
  int l15 = lane&15, l4 = lane>>4;
  f32x4 acc[4][4];
  #pragma unroll
  for (int a=0;a<4;a++)
    #pragma unroll
    for (int b=0;b<4;b++) acc[a][b] = (f32x4){0.f,0.f,0.f,0.f};
  // staging: 8 chunks of 16 rows each for A and B; wave w owns chunks 2w, 2w+1.
  int srow = lane>>2, scol = (lane&3)*8;
  int c0i = 2*w, c1i = 2*w+1;
  const u16* Ap0 = A  + (size_t)(m0 + c0i*16 + srow)*DM + scol;
  const u16* Ap1 = A  + (size_t)(m0 + c1i*16 + srow)*DM + scol;
  const u16* Bp0 = Bt + (size_t)(n0 + c0i*16 + srow)*DM + scol;
  const u16* Bp1 = Bt + (size_t)(n0 + c1i*16 + srow)*DM + scol;
  u16* lA0 = &As[c0i*512];
  u16* lA1 = &As[c1i*512];
  u16* lB0 = &Bs[c0i*512];
  u16* lB1 = &Bs[c1i*512];
  for (int kk=0; kk<DM; kk+=32){
    __syncthreads();
    gld16(Ap0+kk, lA0); gld16(Ap1+kk, lA1);
    gld16(Bp0+kk, lB0); gld16(Bp1+kk, lB1);
    __syncthreads();   // compiler inserts vmcnt(0) drain here
    bf16x8 a[4], b[4];
    #pragma unroll
    for (int f=0; f<4; f++){
      a[f] = *(const bf16x8*)&As[(wr + 16*f + l15)*32 + l4*8];
      b[f] = *(const bf16x8*)&Bs[(wc + 16*f + l15)*32 + l4*8];
    }
    #pragma unroll
    for (int fm=0; fm<4; fm++)
      #pragma unroll
      for (int fn=0; fn<4; fn++)
        acc[fm][fn] = MFMA16(a[fm], b[fn], acc[fm][fn], 0,0,0);
  }
  int rowoff = l4*4;
  #pragma unroll
  for (int fm=0; fm<4; fm++)
    #pragma unroll
    for (int fn=0; fn<4; fn++)
      #pragma unroll
      for (int e=0; e<4; e++)
        Cout[(size_t)(m0+wr+16*fm+rowoff+e)*DM + n0+wc+16*fn+l15] = acc[fm][fn][e];
}

// ------------- small projections x@Wbeta, x@Wg -> [T][8] each -------------
__global__ void proj_small(const float* __restrict__ x, const float* __restrict__ Wb, const float* __restrict__ Wg,
                           float* __restrict__ xWb, float* __restrict__ xWg){
  int w = threadIdx.x>>6, lane = threadIdx.x&63;
  int t = blockIdx.x*4 + w;
  float accB[8], accG[8];
  #pragma unroll
  for (int o=0;o<8;o++){ accB[o]=0.f; accG[o]=0.f; }
  for (int k=lane; k<DM; k+=64){
    float xv = x[(size_t)t*DM + k];
    #pragma unroll
    for (int o=0;o<8;o++){ accB[o] += xv*Wb[k*8+o]; accG[o] += xv*Wg[k*8+o]; }
  }
  #pragma unroll
  for (int o=0;o<8;o++){
    float b = accB[o], g = accG[o];
    #pragma unroll
    for (int d=1; d<64; d<<=1){ b += __shfl_xor(b, d, 64); g += __shfl_xor(g, d, 64); }
    if (lane==0){ xWb[t*8+o] = b; xWg[t*8+o] = g; }
  }
}

// ------------- beta = 2*sigmoid, g = logsigmoid, G = cumsum (per head) -------------
__global__ void scan_g(const float* __restrict__ xWb, const float* __restrict__ xWg,
                       float* __restrict__ beta, float* __restrict__ G){
  int h = threadIdx.x>>6, lane = threadIdx.x&63;
  float off = 0.f;
  for (int tile=0; tile<TLEN/64; ++tile){
    int t = tile*64 + lane;
    float braw = xWb[t*8+h];
    beta[h*TLEN+t] = 2.f/(1.f+expf(-braw));
    float graw = xWg[t*8+h];
    float g = (graw < 0.f) ? (graw - log1pf(expf(graw))) : (-log1pf(expf(-graw)));
    #pragma unroll
    for (int d=1; d<64; d<<=1){ float n = __shfl_up(g, d, 64); if (lane>=d) g += n; }
    G[h*TLEN+t] = g + off;
    off += __shfl(g, 63, 64);
  }
}

// ------------- per-(t,head) RMS norm in place -------------
__global__ void rms_inplace(float* __restrict__ buf, const float* __restrict__ wn){
  int lane = threadIdx.x;
  int t = blockIdx.x>>3, h = blockIdx.x&7;
  size_t base = (size_t)t*DM + h*HD;
  float v0 = buf[base+lane], v1 = buf[base+64+lane];
  float ss = v0*v0 + v1*v1;
  #pragma unroll
  for (int d=1; d<64; d<<=1) ss += __shfl_xor(ss, d, 64);
  float f = rsqrtf(ss*(1.f/128.f) + 1e-6f);
  buf[base+lane] = v0*f*wn[lane];
  buf[base+64+lane] = v1*f*wn[64+lane];
}

// ------------- causal depthwise conv(4) + silu + per-head l2 norm -------------
__global__ void conv_silu_norm(const float* __restrict__ wpre, const float* __restrict__ cw,
                               float* __restrict__ wd){
  int t = blockIdx.x, tid = threadIdx.x;
  int c0 = tid*4;
  float cwa[4][4];
  #pragma unroll
  for (int c=0;c<4;c++){
    float4 v = *(const float4*)&cw[(c0+c)*4];
    cwa[c][0]=v.x; cwa[c][1]=v.y; cwa[c][2]=v.z; cwa[c][3]=v.w;
  }
  float acc[4] = {0.f,0.f,0.f,0.f};
  #pragma unroll
  for (int i=0;i<4;i++){
    int ti = t-3+i;
    if (ti >= 0){
      float4 xv = *(const float4*)&wpre[(size_t)ti*DM + c0];
      acc[0] += xv.x*cwa[0][i]; acc[1] += xv.y*cwa[1][i];
      acc[2] += xv.z*cwa[2][i]; acc[3] += xv.w*cwa[3][i];
    }
  }
  float s[4], ss = 0.f;
  #pragma unroll
  for (int c=0;c<4;c++){ s[c] = acc[c]/(1.f+__expf(-acc[c])); ss += s[c]*s[c]; }
  #pragma unroll
  for (int d=1; d<32; d<<=1) ss += __shfl_xor(ss, d, 64);
  float f = rsqrtf(ss + 1e-6f);
  float4 o = {s[0]*f, s[1]*f, s[2]*f, s[3]*f};
  *(float4*)&wd[(size_t)t*DM + c0] = o;
}

// ------------- gram: per (h,chunk) four 64x64 matrices via split-bf16 MFMA -------------
// plane 0: W.W^T  plane 1: W.K^T  plane 2: Q.W^T  plane 3: Q.K^T
__global__ __launch_bounds__(256) void gram_kernel(
    const u16* __restrict__ Whi, const u16* __restrict__ Wlo,
    const u16* __restrict__ Khi, const u16* __restrict__ Klo,
    const u16* __restrict__ Qhi, const u16* __restrict__ Qlo,
    float* __restrict__ G4){
  int h = blockIdx.x>>5, I = blockIdx.x&31, t0 = I*64;
  int tid = threadIdx.x, lane = tid&63, w = tid>>6;
  int l15 = lane&15, l4 = lane>>4;
  const u16 *Ah, *Al, *Bh, *Bl;
  if (w==0){ Ah=Whi; Al=Wlo; Bh=Whi; Bl=Wlo; }
  else if (w==1){ Ah=Whi; Al=Wlo; Bh=Khi; Bl=Klo; }
  else if (w==2){ Ah=Qhi; Al=Qlo; Bh=Whi; Bl=Wlo; }
  else { Ah=Qhi; Al=Qlo; Bh=Khi; Bl=Klo; }
  size_t rowbase = (size_t)t0*DM + h*HD;
  f32x4 acc[4][4];
  #pragma unroll
  for (int a=0;a<4;a++)
    #pragma unroll
    for (int b=0;b<4;b++) acc[a][b] = (f32x4){0.f,0.f,0.f,0.f};
  #pragma unroll 1
  for (int ks=0; ks<4; ++ks){
    bf16x8 ah[4], al[4], bh[4], bl[4];
    #pragma unroll
    for (int f=0; f<4; f++){
      size_t off = rowbase + (size_t)(16*f + l15)*DM + ks*32 + l4*8;
      ah[f] = *(const bf16x8*)(Ah + off);
      al[f] = *(const bf16x8*)(Al + off);
      bh[f] = *(const bf16x8*)(Bh + off);
      bl[f] = *(const bf16x8*)(Bl + off);
    }
    #pragma unroll
    for (int fm=0; fm<4; fm++)
      #pragma unroll
      for (int fn=0; fn<4; fn++){
        acc[fm][fn] = MFMA16(ah[fm], bh[fn], acc[fm][fn], 0,0,0);
        acc[fm][fn] = MFMA16(ah[fm], bl[fn], acc[fm][fn], 0,0,0);
        acc[fm][fn] = MFMA16(al[fm], bh[fn], acc[fm][fn], 0,0,0);
      }
  }
  float* out = G4 + ((size_t)(h*32+I)*4 + w)*4096;
  #pragma unroll
  for (int fm=0; fm<4; fm++)
    #pragma unroll
    for (int fn=0; fn<4; fn++)
      #pragma unroll
      for (int e=0; e<4; e++)
        out[(16*fm + l4*4 + e)*64 + 16*fn + l15] = acc[fm][fn][e];
}

// ------------- solve: per (h,chunk) forward substitution for b_k, b_w -------------
__global__ __launch_bounds__(128) void solve_kernel(float* __restrict__ G4, const float* __restrict__ betaB){
  int h = blockIdx.x>>5, I = blockIdx.x&31, t0 = I*64;
  int tid = threadIdx.x;
  __shared__ float M[64][68];
  __shared__ float bet[64];
  float* base = G4 + (size_t)(h*32+I)*4*4096;
  float* Sww = base;
  float* WK  = base + 4096;
  if (tid < 64) bet[tid] = betaB[h*TLEN + t0 + tid];
  __syncthreads();
  #pragma unroll 1
  for (int i=0;i<32;i++){
    int idx = i*128 + tid;
    int s = idx>>6, r = idx&63;
    M[s][r] = (s>r) ? Sww[idx]*bet[r] : 0.f;
  }
  __syncthreads();
  int col = tid & 63;
  const float* src = (tid < 64) ? WK : Sww;
  float x[64];
  #pragma unroll
  for (int s=0;s<64;++s){
    float v = src[s*64 + col];
    x[s] = (s > col) ? v : 0.f;
  }
  __syncthreads();
  #pragma unroll
  for (int s=1; s<64; ++s){
    float a0=0.f, a1=0.f, a2=0.f, a3=0.f;
    #pragma unroll
    for (int r=0; r<(s&~3); r+=4){
      a0 += M[s][r  ]*x[r  ];
      a1 += M[s][r+1]*x[r+1];
      a2 += M[s][r+2]*x[r+2];
      a3 += M[s][r+3]*x[r+3];
    }
    #pragma unroll
    for (int r=(s&~3); r<s; ++r) a0 += M[s][r]*x[r];
    x[s] -= (a0+a1)+(a2+a3);
  }
  #pragma unroll
  for (int s=0;s<64;++s) x[s] *= bet[s];
  float* out = (tid < 64 ? Sww : WK) + (size_t)col*64;
  #pragma unroll
  for (int s=0;s<64;s+=4){
    float4 o = {x[s], x[s+1], x[s+2], x[s+3]};
    *(float4*)&out[s] = o;
  }
}

// ------------- post (MFMA): per (h,chunk) A_diag, -C, Qtilde, Ktilde -------------
__global__ __launch_bounds__(256) void post_kernel(
    const float* __restrict__ G4, const float* __restrict__ Qn, const float* __restrict__ Kn,
    const u16* __restrict__ Whi, const float* __restrict__ betaB,
    float* __restrict__ Adiag, u16* __restrict__ Qt, u16* __restrict__ Ktb){
  int h = blockIdx.x>>5, I = blockIdx.x&31, t0 = I*64;
  int tid = threadIdx.x, lane = tid&63, w = tid>>6;
  int l15 = lane&15, l4 = lane>>4;
  const float* XkT = G4 + (size_t)(h*32+I)*4*4096;   // [j][s]
  const float* XwT = XkT + 4096;                      // [s][r]
  const float* QW  = XkT + 2*4096;                    // [t][s]
  const float* QK  = XkT + 3*4096;                    // [t][j]
  __shared__ u16 WT[128][72];
  __shared__ u16 Ch[64][72];
  __shared__ u16 Cl[64][72];
  {
    int d = tid>>1, half = (tid&1)*32;
    u16 tmp[32];
    #pragma unroll
    for (int i=0;i<32;i++)
      tmp[i] = Whi[(size_t)(t0+half+i)*DM + h*HD + d];
    #pragma unroll
    for (int i=0;i<32;i+=8){
      U16x8 u;
      #pragma unroll
      for (int e=0;e<8;e++) u.us[e] = tmp[i+e];
      *(uint4*)&WT[d][half+i] = u.u4;
    }
  }
  bf16x8 Dh[2], Dl[2];
  {
    int t = 16*w + l15;
    #pragma unroll
    for (int ks=0; ks<2; ++ks){
      const float* p = QW + t*64 + ks*32 + l4*8;
      U16x8 hh, ll;
      #pragma unroll
      for (int e=0;e<8;e++){
        int s = ks*32 + l4*8 + e;
        float v = (s<=t) ? p[e] : 0.f;
        u16 hv = f2bf(v);
        hh.us[e] = hv; ll.us[e] = f2bf(v - bf2f(hv));
      }
      Dh[ks] = hh.bf; Dl[ks] = ll.bf;
    }
  }
  int mrow = 16*w + l4*4;
  {
    float* outp = Adiag + (size_t)(h*32+I)*64*64;
    #pragma unroll 1
    for (int fn=0; fn<4; ++fn){
      f32x4 acc;
      #pragma unroll
      for (int e=0;e<4;e++) acc[e] = QK[(mrow+e)*64 + 16*fn + l15];
      #pragma unroll
      for (int ks=0; ks<2; ++ks){
        const float* p = XkT + (16*fn+l15)*64 + ks*32 + l4*8;
        U16x8 bh, bl;
        #pragma unroll
        for (int e=0;e<8;e++){
          float v = -p[e];
          u16 hv = f2bf(v); bh.us[e]=hv; bl.us[e]=f2bf(v - bf2f(hv));
        }
        acc = MFMA16(Dh[ks], bh.bf, acc, 0,0,0);
        acc = MFMA16(Dh[ks], bl.bf, acc, 0,0,0);
        acc = MFMA16(Dl[ks], bh.bf, acc, 0,0,0);
      }
      #pragma unroll
      for (int e=0;e<4;e++) outp[(mrow+e)*64 + 16*fn + l15] = acc[e];
    }
  }
  {
    #pragma unroll 1
    for (int fn=0; fn<4; ++fn){
      f32x4 acc = (f32x4){0.f,0.f,0.f,0.f};
      #pragma unroll
      for (int ks=0; ks<2; ++ks){
        const float* p = XwT + (16*fn+l15)*64 + ks*32 + l4*8;
        U16x8 bh, bl;
        #pragma unroll
        for (int e=0;e<8;e++){
          float v = -p[e];
          u16 hv = f2bf(v); bh.us[e]=hv; bl.us[e]=f2bf(v - bf2f(hv));
        }
        acc = MFMA16(Dh[ks], bh.bf, acc, 0,0,0);
        acc = MFMA16(Dh[ks], bl.bf, acc, 0,0,0);
        acc = MFMA16(Dl[ks], bh.bf, acc, 0,0,0);
      }
      int s = 16*fn + l15;
      float bet = betaB[h*TLEN + t0 + s];
      #pragma unroll
      for (int e=0;e<4;e++){
        int t = mrow + e;
        float Dts = (s<=t) ? QW[t*64+s] : 0.f;
        float mc = -bet*(Dts + acc[e]);
        u16 hv = f2bf(mc);
        Ch[t][s] = hv;
        Cl[t][s] = f2bf(mc - bf2f(hv));
      }
    }
  }
  __syncthreads();
  {
    bf16x8 Ah[2], Al[2];
    int j = 16*w + l15;
    #pragma unroll
    for (int ks=0; ks<2; ++ks){
      const float* p = XkT + j*64 + ks*32 + l4*8;
      U16x8 hh, ll;
      #pragma unroll
      for (int e=0;e<8;e++){
        float v = -p[e];
        u16 hv = f2bf(v); hh.us[e]=hv; ll.us[e]=f2bf(v - bf2f(hv));
      }
      Ah[ks] = hh.bf; Al[ks] = ll.bf;
    }
    f32x4 acc[8];
    #pragma unroll
    for (int fn=0; fn<8; ++fn)
      #pragma unroll
      for (int e=0;e<4;e++)
        acc[fn][e] = Kn[(size_t)(t0+mrow+e)*DM + h*HD + 16*fn + l15];
    #pragma unroll
    for (int ks=0; ks<2; ++ks)
      #pragma unroll
      for (int fn=0; fn<8; ++fn){
        bf16x8 b = *(const bf16x8*)&WT[16*fn+l15][ks*32 + l4*8];
        acc[fn] = MFMA16(Ah[ks], b, acc[fn], 0,0,0);
        acc[fn] = MFMA16(Al[ks], b, acc[fn], 0,0,0);
      }
    #pragma unroll
    for (int fn=0; fn<8; ++fn)
      #pragma unroll
      for (int e=0;e<4;e++)
        Ktb[((size_t)h*TLEN + t0+mrow+e)*HD + 16*fn + l15] = f2bf(acc[fn][e]);
  }
  {
    bf16x8 Ah[2], Al[2];
    int t = 16*w + l15;
    #pragma unroll
    for (int ks=0; ks<2; ++ks){
      Ah[ks] = *(const bf16x8*)&Ch[t][ks*32 + l4*8];
      Al[ks] = *(const bf16x8*)&Cl[t][ks*32 + l4*8];
    }
    f32x4 acc[8];
    #pragma unroll
    for (int fn=0; fn<8; ++fn)
      #pragma unroll
      for (int e=0;e<4;e++)
        acc[fn][e] = Qn[(size_t)(t0+mrow+e)*DM + h*HD + 16*fn + l15];
    #pragma unroll
    for (int ks=0; ks<2; ++ks)
      #pragma unroll
      for (int fn=0; fn<8; ++fn){
        bf16x8 b = *(const bf16x8*)&WT[16*fn+l15][ks*32 + l4*8];
        acc[fn] = MFMA16(Ah[ks], b, acc[fn], 0,0,0);
        acc[fn] = MFMA16(Al[ks], b, acc[fn], 0,0,0);
      }
    #pragma unroll
    for (int fn=0; fn<8; ++fn)
      #pragma unroll
      for (int e=0;e<4;e++)
        Qt[((size_t)h*TLEN + t0+mrow+e)*HD + 16*fn + l15] = f2bf(acc[fn][e]);
  }
}

// ------------- fused windowed attention: per (head, chunk I) -------------
__global__ __launch_bounds__(256) void attn_win(const u16* __restrict__ Qt, const u16* __restrict__ Ktb,
    const float* __restrict__ Adiag, const float* __restrict__ G,
    const u16* __restrict__ Vt, u16* __restrict__ obuf){
  int h = blockIdx.x>>5, I = blockIdx.x&31;
  int tid = threadIdx.x, lane = tid&63, w = tid>>6;
  int l15 = lane&15, l4 = lane>>4;
  __shared__ float S[64][136];
  __shared__ u16 P[64][136];

  if (I > 0){
    f32x4 acc4[4];
    #pragma unroll
    for (int f=0;f<4;f++) acc4[f] = (f32x4){0.f,0.f,0.f,0.f};
    #pragma unroll 1
    for (int ks=0; ks<4; ++ks){
      bf16x8 af = *(const bf16x8*)(Qt + ((size_t)h*TLEN + I*64 + 16*w + l15)*HD + ks*32 + l4*8);
      #pragma unroll
      for (int fn=0; fn<4; ++fn){
        bf16x8 bf = *(const bf16x8*)(Ktb + ((size_t)h*TLEN + (I-1)*64 + 16*fn + l15)*HD + ks*32 + l4*8);
        acc4[fn] = MFMA16(af, bf, acc4[fn], 0,0,0);
      }
    }
    #pragma unroll
    for (int fn=0; fn<4; ++fn)
      #pragma unroll
      for (int e=0;e<4;e++)
        S[16*w + l4*4 + e][16*fn + l15] = acc4[fn][e];
  }
  #pragma unroll 1
  for (int i=0;i<16;i++){
    int idx = i*256 + tid;
    int tq = idx>>6, j = idx&63;
    S[tq][64+j] = Adiag[((size_t)(h*32+I)*64 + tq)*64 + j];
    if (I == 0) S[tq][j] = 0.f;
  }
  __syncthreads();

  {
    int r = tid>>2, qd = tid&3, c0 = qd*32;
    int t = I*64 + r;
    float Gt = G[h*TLEN + t];
    const float scale = 0.08838834764831845f;
    int base = I*64 - 64;
    float lg[32];
    float mx = -1e30f;
    #pragma unroll
    for (int e=0;e<32;e++){
      int c = c0 + e;
      int j = base + c;
      float gj = G[h*TLEN + (j<0?0:j)];
      float v = (j>=0 && j<=t) ? (S[r][c]*scale + Gt - gj) : -1e30f;
      lg[e] = v;
      mx = fmaxf(mx, v);
    }
    mx = fmaxf(mx, __shfl_xor(mx, 1, 64));
    mx = fmaxf(mx, __shfl_xor(mx, 2, 64));
    float sum = 0.f;
    #pragma unroll
    for (int e=0;e<32;e++){ float p = __expf(lg[e]-mx); lg[e] = p; sum += p; }
    sum += __shfl_xor(sum, 1, 64);
    sum += __shfl_xor(sum, 2, 64);
    float inv = 1.f/sum;
    #pragma unroll
    for (int e8=0;e8<4;e8++){
      U16x8 u;
      #pragma unroll
      for (int e=0;e<8;e++) u.us[e] = f2bf(lg[e8*8+e]*inv);
      *(uint4*)&P[r][c0 + e8*8] = u.u4;
    }
  }
  __syncthreads();

  {
    f32x4 acc[8];
    #pragma unroll
    for (int f=0;f<8;f++) acc[f] = (f32x4){0.f,0.f,0.f,0.f};
    #pragma unroll 1
    for (int ks=0; ks<4; ++ks){
      bf16x8 pa = *(const bf16x8*)&P[16*w + l15][ks*32 + l4*8];
      int jb = (I-1)*64 + ks*32 + l4*8;
      if (jb < 0) jb = 0;
      #pragma unroll
      for (int fd=0; fd<8; ++fd){
        bf16x8 vb = *(const bf16x8*)(Vt + ((size_t)(h*HD + l15 + 16*fd))*TLEN + jb);
        acc[fd] = MFMA16(pa, vb, acc[fd], 0,0,0);
      }
    }
    #pragma unroll
    for (int fd=0; fd<8; ++fd)
      #pragma unroll
      for (int e=0;e<4;e++)
        obuf[(size_t)(I*64 + 16*w + l4*4 + e)*DM + h*HD + l15 + 16*fd] = f2bf(acc[fd][e]);
  }
}

extern "C" void kernel_launch(void* const* d_in, const int* in_sizes, int n_in,
                              void* d_out, int out_size, void* d_ws, size_t ws_size,
                              hipStream_t stream){
  const float* x     = (const float*)d_in[0];
  const float* Wq    = (const float*)d_in[1];
  const float* Wk    = (const float*)d_in[2];
  const float* Wv    = (const float*)d_in[3];
  const float* Ww    = (const float*)d_in[4];
  const float* Wbeta = (const float*)d_in[5];
  const float* Wg    = (const float*)d_in[6];
  const float* Wo    = (const float*)d_in[7];
  const float* convw = (const float*)d_in[8];
  const float* qnw   = (const float*)d_in[9];
  const float* knw   = (const float*)d_in[10];

  char* ws = (char*)d_ws;
  size_t off = 0;
  auto take = [&](size_t n)->char*{ char* p = ws + off; off += (n + 255) & ~(size_t)255; return p; };

  u16*  xb    = (u16*)take((size_t)TLEN*DM*2);      // aliased later by obuf
  u16*  WqT   = (u16*)take((size_t)DM*DM*2);
  u16*  WkT   = (u16*)take((size_t)DM*DM*2);
  u16*  WvT   = (u16*)take((size_t)DM*DM*2);
  u16*  WwT   = (u16*)take((size_t)DM*DM*2);
  u16*  WoT   = (u16*)take((size_t)DM*DM*2);
  float* Qn   = (float*)take((size_t)TLEN*DM*4);
  float* Kn   = (float*)take((size_t)TLEN*DM*4);
  float* Vraw = (float*)take((size_t)TLEN*DM*4);    // aliased later by Adiag
  float* Wpre = (float*)take((size_t)TLEN*DM*4);
  float* Wdir = (float*)take((size_t)TLEN*DM*4);
  u16*  Vt    = (u16*)take((size_t)DM*TLEN*2);
  float* xWb  = (float*)take((size_t)TLEN*8*4);
  float* xWg  = (float*)take((size_t)TLEN*8*4);
  float* betaB= (float*)take((size_t)NH*TLEN*4);
  float* GB   = (float*)take((size_t)NH*TLEN*4);
  u16*  Qt    = (u16*)take((size_t)NH*TLEN*HD*2);
  u16*  Ktb   = (u16*)take((size_t)NH*TLEN*HD*2);
  u16*  Whi   = (u16*)take((size_t)TLEN*DM*2);
  u16*  Wlo   = (u16*)take((size_t)TLEN*DM*2);
  u16*  Khi   = (u16*)take((size_t)TLEN*DM*2);
  u16*  Klo   = (u16*)take((size_t)TLEN*DM*2);
  u16*  Qhi   = (u16*)take((size_t)TLEN*DM*2);
  u16*  Qlo   = (u16*)take((size_t)TLEN*DM*2);
  float* G4   = (float*)take((size_t)NH*32*4*64*64*4);   // 16 MB

  float* Adiag = (float*)Vraw;   // 4 MB needed; Vraw dead after Vt transpose
  u16*  obuf  = xb;              // 4 MB; xb dead after the 4 projection GEMMs

  cast_f32_bf16<<<dim3(TLEN*DM/(256*8)), dim3(256), 0, stream>>>(x, xb, TLEN*DM);
  transpose_cast<<<dim3(16,16), dim3(256), 0, stream>>>(Wq, WqT, DM, DM);
  transpose_cast<<<dim3(16,16), dim3(256), 0, stream>>>(Wk, WkT, DM, DM);
  transpose_cast<<<dim3(16,16), dim3(256), 0, stream>>>(Wv, WvT, DM, DM);
  transpose_cast<<<dim3(16,16), dim3(256), 0, stream>>>(Ww, WwT, DM, DM);
  transpose_cast<<<dim3(16,16), dim3(256), 0, stream>>>(Wo, WoT, DM, DM);

  // all 4 projections in ONE launch: 512 blocks = full chip, global_load_lds staging
  gemm4<<<dim3(32,16), dim3(256), 0, stream>>>(xb, WqT, WkT, WvT, WwT, Qn, Kn, Vraw, Wpre);

  proj_small<<<dim3(TLEN/4), dim3(256), 0, stream>>>(x, Wbeta, Wg, xWb, xWg);
  scan_g<<<dim3(1), dim3(512), 0, stream>>>(xWb, xWg, betaB, GB);

  rms_inplace<<<dim3(TLEN*NH), dim3(64), 0, stream>>>(Qn, qnw);
  rms_inplace<<<dim3(TLEN*NH), dim3(64), 0, stream>>>(Kn, knw);
  conv_silu_norm<<<dim3(TLEN), dim3(256), 0, stream>>>(Wpre, convw, Wdir);
  transpose_cast<<<dim3(16,32), dim3(256), 0, stream>>>(Vraw, Vt, TLEN, DM);   // Vraw dead after this

  precast_hilo<<<dim3(TLEN*DM/(256*8)), dim3(256), 0, stream>>>(Wdir, Whi, Wlo, TLEN*DM);
  precast_hilo<<<dim3(TLEN*DM/(256*8)), dim3(256), 0, stream>>>(Kn,   Khi, Klo, TLEN*DM);
  precast_hilo<<<dim3(TLEN*DM/(256*8)), dim3(256), 0, stream>>>(Qn,   Qhi, Qlo, TLEN*DM);

  gram_kernel<<<dim3(256), dim3(256), 0, stream>>>(Whi, Wlo, Khi, Klo, Qhi, Qlo, G4);
  solve_kernel<<<dim3(256), dim3(128), 0, stream>>>(G4, betaB);
  post_kernel<<<dim3(256), dim3(256), 0, stream>>>(G4, Qn, Kn, Whi, betaB, Adiag, Qt, Ktb);

  attn_win<<<dim3(256), dim3(256), 0, stream>>>(Qt, Ktb, Adiag, GB, Vt, obuf);

  // FINAL PROJECTION — d_out is FLOAT32; single-B use of gemm4 (bsel always 0)
  gemm4<<<dim3(8,16), dim3(256), 0, stream>>>(obuf, WoT, WoT, WoT, WoT,
                                              (float*)d_out, (float*)d_out, (float*)d_out, (float*)d_out);
}

// Round 8
// 268.855 us; speedup vs baseline: 1.7827x; 1.1505x over previous
//
#include <hip/hip_runtime.h>

#define TLEN 2048
#define DM 1024
#define NH 8
#define HD 128

typedef unsigned short u16;
typedef __bf16 bf16_t;
typedef bf16_t bf16x8 __attribute__((ext_vector_type(8)));
typedef float f32x4 __attribute__((ext_vector_type(4)));
typedef unsigned short ushort8 __attribute__((ext_vector_type(8)));

union U16x8 { uint4 u4; ushort8 us; bf16x8 bf; };

__device__ __forceinline__ u16 f2bf(float f){
  unsigned u = __float_as_uint(f);
  u += 0x7FFFu + ((u>>16)&1u);
  return (u16)(u>>16);
}
__device__ __forceinline__ float bf2f(u16 u){ return __uint_as_float(((unsigned)u)<<16); }

#define MFMA16 __builtin_amdgcn_mfma_f32_16x16x32_bf16

// async global->LDS, 16B per lane; lds dst must be wave-uniform base (HW adds lane*16)
__device__ __forceinline__ void gld16(const u16* g, u16* l){
  __builtin_amdgcn_global_load_lds((const __attribute__((address_space(1))) unsigned*)g,
                                   (__attribute__((address_space(3))) unsigned*)l, 16, 0, 0);
}

// ---------------- elementwise cast f32 -> bf16 ----------------
__global__ void cast_f32_bf16(const float* __restrict__ in, u16* __restrict__ out, int n){
  int i = (blockIdx.x*256 + threadIdx.x)*8;
  if (i >= n) return;
  float4 a = *(const float4*)&in[i];
  float4 b = *(const float4*)&in[i+4];
  U16x8 r;
  r.us[0]=f2bf(a.x); r.us[1]=f2bf(a.y); r.us[2]=f2bf(a.z); r.us[3]=f2bf(a.w);
  r.us[4]=f2bf(b.x); r.us[5]=f2bf(b.y); r.us[6]=f2bf(b.z); r.us[7]=f2bf(b.w);
  *(uint4*)&out[i] = r.u4;
}

// ------------- batched transpose + cast: 5 weight matrices [DM][DM] -> bf16 [DM][DM]^T -------------
__global__ void transpose_cast5(const float* __restrict__ s0, const float* __restrict__ s1,
                                const float* __restrict__ s2, const float* __restrict__ s3,
                                const float* __restrict__ s4,
                                u16* __restrict__ d0, u16* __restrict__ d1, u16* __restrict__ d2,
                                u16* __restrict__ d3, u16* __restrict__ d4){
  __shared__ float t[64][65];
  int z = blockIdx.z;
  const float* in = (z==0)?s0:(z==1)?s1:(z==2)?s2:(z==3)?s3:s4;
  u16* out        = (z==0)?d0:(z==1)?d1:(z==2)?d2:(z==3)?d3:d4;
  const int R = DM, C = DM;
  int r0 = blockIdx.y*64, c0 = blockIdx.x*64;
  int tid = threadIdx.x;
  int r = tid>>2, q = tid&3;
  const float* ip = in + (size_t)(r0+r)*C + c0 + q*16;
  #pragma unroll
  for (int i=0;i<4;i++){
    float4 v = *(const float4*)(ip + i*4);
    t[r][q*16+i*4+0]=v.x; t[r][q*16+i*4+1]=v.y; t[r][q*16+i*4+2]=v.z; t[r][q*16+i*4+3]=v.w;
  }
  __syncthreads();
  int oc = tid>>2;
  U16x8 lo, hi;
  #pragma unroll
  for (int i=0;i<8;i++) lo.us[i] = f2bf(t[q*16+i][oc]);
  #pragma unroll
  for (int i=0;i<8;i++) hi.us[i] = f2bf(t[q*16+8+i][oc]);
  u16* op = out + (size_t)(c0+oc)*R + r0 + q*16;
  *(uint4*)&op[0] = lo.u4;
  *(uint4*)&op[8] = hi.u4;
}

// ------------- single transpose + cast (for V) -------------
__global__ void transpose_cast(const float* __restrict__ in, u16* __restrict__ out, int R, int C){
  __shared__ float t[64][65];
  int r0 = blockIdx.y*64, c0 = blockIdx.x*64;
  int tid = threadIdx.x;
  int r = tid>>2, q = tid&3;
  const float* ip = in + (size_t)(r0+r)*C + c0 + q*16;
  #pragma unroll
  for (int i=0;i<4;i++){
    float4 v = *(const float4*)(ip + i*4);
    t[r][q*16+i*4+0]=v.x; t[r][q*16+i*4+1]=v.y; t[r][q*16+i*4+2]=v.z; t[r][q*16+i*4+3]=v.w;
  }
  __syncthreads();
  int oc = tid>>2;
  U16x8 lo, hi;
  #pragma unroll
  for (int i=0;i<8;i++) lo.us[i] = f2bf(t[q*16+i][oc]);
  #pragma unroll
  for (int i=0;i<8;i++) hi.us[i] = f2bf(t[q*16+8+i][oc]);
  u16* op = out + (size_t)(c0+oc)*R + r0 + q*16;
  *(uint4*)&op[0] = lo.u4;
  *(uint4*)&op[8] = hi.u4;
}

// ------------- batched bf16 GEMM (m97-style global_load_lds staging) -------------
__global__ __launch_bounds__(256) void gemm4(const u16* __restrict__ A,
    const u16* __restrict__ B0, const u16* __restrict__ B1,
    const u16* __restrict__ B2, const u16* __restrict__ B3,
    float* __restrict__ C0, float* __restrict__ C1,
    float* __restrict__ C2, float* __restrict__ C3){
  __shared__ u16 As[128*32];
  __shared__ u16 Bs[128*32];
  int tid = threadIdx.x, lane = tid&63, w = tid>>6;
  int bsel = blockIdx.x>>3;
  const u16* Bt = (bsel==0)?B0 : (bsel==1)?B1 : (bsel==2)?B2 : B3;
  float* Cout   = (bsel==0)?C0 : (bsel==1)?C1 : (bsel==2)?C2 : C3;
  int m0 = blockIdx.y*128, n0 = (blockIdx.x&7)*128;
  int wr = (w>>1)*64, wc = (w&1)*64;
  int l15 = lane&15, l4 = lane>>4;
  f32x4 acc[4][4];
  #pragma unroll
  for (int a=0;a<4;a++)
    #pragma unroll
    for (int b=0;b<4;b++) acc[a][b] = (f32x4){0.f,0.f,0.f,0.f};
  int srow = lane>>2, scol = (lane&3)*8;
  int c0i = 2*w, c1i = 2*w+1;
  const u16* Ap0 = A  + (size_t)(m0 + c0i*16 + srow)*DM + scol;
  const u16* Ap1 = A  + (size_t)(m0 + c1i*16 + srow)*DM + scol;
  const u16* Bp0 = Bt + (size_t)(n0 + c0i*16 + srow)*DM + scol;
  const u16* Bp1 = Bt + (size_t)(n0 + c1i*16 + srow)*DM + scol;
  u16* lA0 = &As[c0i*512];
  u16* lA1 = &As[c1i*512];
  u16* lB0 = &Bs[c0i*512];
  u16* lB1 = &Bs[c1i*512];
  for (int kk=0; kk<DM; kk+=32){
    __syncthreads();
    gld16(Ap0+kk, lA0); gld16(Ap1+kk, lA1);
    gld16(Bp0+kk, lB0); gld16(Bp1+kk, lB1);
    __syncthreads();
    bf16x8 a[4], b[4];
    #pragma unroll
    for (int f=0; f<4; f++){
      a[f] = *(const bf16x8*)&As[(wr + 16*f + l15)*32 + l4*8];
      b[f] = *(const bf16x8*)&Bs[(wc + 16*f + l15)*32 + l4*8];
    }
    #pragma unroll
    for (int fm=0; fm<4; fm++)
      #pragma unroll
      for (int fn=0; fn<4; fn++)
        acc[fm][fn] = MFMA16(a[fm], b[fn], acc[fm][fn], 0,0,0);
  }
  int rowoff = l4*4;
  #pragma unroll
  for (int fm=0; fm<4; fm++)
    #pragma unroll
    for (int fn=0; fn<4; fn++)
      #pragma unroll
      for (int e=0; e<4; e++)
        Cout[(size_t)(m0+wr+16*fm+rowoff+e)*DM + n0+wc+16*fn+l15] = acc[fm][fn][e];
}

// ------------- small projections x@Wbeta, x@Wg -> [T][8] each -------------
__global__ void proj_small(const float* __restrict__ x, const float* __restrict__ Wb, const float* __restrict__ Wg,
                           float* __restrict__ xWb, float* __restrict__ xWg){
  int w = threadIdx.x>>6, lane = threadIdx.x&63;
  int t = blockIdx.x*4 + w;
  float accB[8], accG[8];
  #pragma unroll
  for (int o=0;o<8;o++){ accB[o]=0.f; accG[o]=0.f; }
  for (int k=lane; k<DM; k+=64){
    float xv = x[(size_t)t*DM + k];
    #pragma unroll
    for (int o=0;o<8;o++){ accB[o] += xv*Wb[k*8+o]; accG[o] += xv*Wg[k*8+o]; }
  }
  #pragma unroll
  for (int o=0;o<8;o++){
    float b = accB[o], g = accG[o];
    #pragma unroll
    for (int d=1; d<64; d<<=1){ b += __shfl_xor(b, d, 64); g += __shfl_xor(g, d, 64); }
    if (lane==0){ xWb[t*8+o] = b; xWg[t*8+o] = g; }
  }
}

// ------------- beta = 2*sigmoid, g = logsigmoid, G = cumsum (per head) -------------
__global__ void scan_g(const float* __restrict__ xWb, const float* __restrict__ xWg,
                       float* __restrict__ beta, float* __restrict__ G){
  int h = threadIdx.x>>6, lane = threadIdx.x&63;
  float off = 0.f;
  for (int tile=0; tile<TLEN/64; ++tile){
    int t = tile*64 + lane;
    float braw = xWb[t*8+h];
    beta[h*TLEN+t] = 2.f/(1.f+expf(-braw));
    float graw = xWg[t*8+h];
    float g = (graw < 0.f) ? (graw - log1pf(expf(graw))) : (-log1pf(expf(-graw)));
    #pragma unroll
    for (int d=1; d<64; d<<=1){ float n = __shfl_up(g, d, 64); if (lane>=d) g += n; }
    G[h*TLEN+t] = g + off;
    off += __shfl(g, 63, 64);
  }
}

// ------------- fused RMS norm + hi/lo split cast for Q and K -------------
// grid 2*TLEN*NH blocks of 64; first half Q, second half K
__global__ void rms_hilo(float* __restrict__ Qn, float* __restrict__ Kn,
                         const float* __restrict__ qnw, const float* __restrict__ knw,
                         u16* __restrict__ Qhi, u16* __restrict__ Qlo,
                         u16* __restrict__ Khi, u16* __restrict__ Klo){
  int b = blockIdx.x;
  int sel = b >> 14;
  int tb = b & 16383;
  float* buf = sel ? Kn : Qn;
  const float* wn = sel ? knw : qnw;
  u16* hi = sel ? Khi : Qhi;
  u16* lo = sel ? Klo : Qlo;
  int lane = threadIdx.x;
  int t = tb>>3, h = tb&7;
  size_t base = (size_t)t*DM + h*HD;
  float v0 = buf[base+lane], v1 = buf[base+64+lane];
  float ss = v0*v0 + v1*v1;
  #pragma unroll
  for (int d=1; d<64; d<<=1) ss += __shfl_xor(ss, d, 64);
  float f = rsqrtf(ss*(1.f/128.f) + 1e-6f);
  float o0 = v0*f*wn[lane], o1 = v1*f*wn[64+lane];
  buf[base+lane] = o0;
  buf[base+64+lane] = o1;
  u16 h0 = f2bf(o0), h1 = f2bf(o1);
  hi[base+lane] = h0;      lo[base+lane] = f2bf(o0 - bf2f(h0));
  hi[base+64+lane] = h1;   lo[base+64+lane] = f2bf(o1 - bf2f(h1));
}

// ------------- causal depthwise conv(4) + silu + per-head l2 norm -> bf16 hi/lo -------------
__global__ void conv_hilo(const float* __restrict__ wpre, const float* __restrict__ cw,
                          u16* __restrict__ whi, u16* __restrict__ wlo){
  int t = blockIdx.x, tid = threadIdx.x;
  int c0 = tid*4;
  float cwa[4][4];
  #pragma unroll
  for (int c=0;c<4;c++){
    float4 v = *(const float4*)&cw[(c0+c)*4];
    cwa[c][0]=v.x; cwa[c][1]=v.y; cwa[c][2]=v.z; cwa[c][3]=v.w;
  }
  float acc[4] = {0.f,0.f,0.f,0.f};
  #pragma unroll
  for (int i=0;i<4;i++){
    int ti = t-3+i;
    if (ti >= 0){
      float4 xv = *(const float4*)&wpre[(size_t)ti*DM + c0];
      acc[0] += xv.x*cwa[0][i]; acc[1] += xv.y*cwa[1][i];
      acc[2] += xv.z*cwa[2][i]; acc[3] += xv.w*cwa[3][i];
    }
  }
  float s[4], ss = 0.f;
  #pragma unroll
  for (int c=0;c<4;c++){ s[c] = acc[c]/(1.f+__expf(-acc[c])); ss += s[c]*s[c]; }
  #pragma unroll
  for (int d=1; d<32; d<<=1) ss += __shfl_xor(ss, d, 64);
  float f = rsqrtf(ss + 1e-6f);
  unsigned ph0, ph1, pl0, pl1;
  u16 hh[4], ll[4];
  #pragma unroll
  for (int c=0;c<4;c++){
    float v = s[c]*f;
    hh[c] = f2bf(v);
    ll[c] = f2bf(v - bf2f(hh[c]));
  }
  ph0 = (unsigned)hh[0] | ((unsigned)hh[1]<<16);
  ph1 = (unsigned)hh[2] | ((unsigned)hh[3]<<16);
  pl0 = (unsigned)ll[0] | ((unsigned)ll[1]<<16);
  pl1 = (unsigned)ll[2] | ((unsigned)ll[3]<<16);
  uint2 uh = {ph0, ph1}, ul = {pl0, pl1};
  *(uint2*)&whi[(size_t)t*DM + c0] = uh;
  *(uint2*)&wlo[(size_t)t*DM + c0] = ul;
}

// ------------- fused chunk: gram (MFMA, LDS planes) + solve (reg) + post (MFMA) -------------
// per (h, chunk I), 256 threads, ~124 KB LDS, 1 block/CU
__global__ __launch_bounds__(256,1) void chunk_fused(
    const u16* __restrict__ Whi, const u16* __restrict__ Wlo,
    const u16* __restrict__ Khi, const u16* __restrict__ Klo,
    const u16* __restrict__ Qhi, const u16* __restrict__ Qlo,
    const float* __restrict__ Qn, const float* __restrict__ Kn,
    const float* __restrict__ betaB,
    float* __restrict__ Adiag, u16* __restrict__ Qt, u16* __restrict__ Ktb){
  int h = blockIdx.x>>5, I = blockIdx.x&31, t0 = I*64;
  int tid = threadIdx.x, lane = tid&63, w = tid>>6;
  int l15 = lane&15, l4 = lane>>4;
  // plane 0: W.W^T -> XkT ; plane 1: W.K^T -> XwT ; plane 2: Q.W^T ; plane 3: Q.K^T
  __shared__ float P[4][64][68];
  __shared__ float M[64][68];
  __shared__ u16 WT[128][72];
  __shared__ u16 Ch[64][72];
  __shared__ u16 Cl[64][72];
  __shared__ float bet[64];

  // stage WT[d][s] = Whi[t0+s][h*HD+d]
  {
    int d = tid>>1, half = (tid&1)*32;
    u16 tmp[32];
    #pragma unroll
    for (int i=0;i<32;i++)
      tmp[i] = Whi[(size_t)(t0+half+i)*DM + h*HD + d];
    #pragma unroll
    for (int i=0;i<32;i+=8){
      U16x8 u;
      #pragma unroll
      for (int e=0;e<8;e++) u.us[e] = tmp[i+e];
      *(uint4*)&WT[d][half+i] = u.u4;
    }
  }
  if (tid < 64) bet[tid] = betaB[h*TLEN + t0 + tid];

  // ---- gram: wave w computes plane w via 3-pass split-bf16 MFMA ----
  {
    const u16 *Ah, *Al, *Bh, *Bl;
    if (w==0){ Ah=Whi; Al=Wlo; Bh=Whi; Bl=Wlo; }
    else if (w==1){ Ah=Whi; Al=Wlo; Bh=Khi; Bl=Klo; }
    else if (w==2){ Ah=Qhi; Al=Qlo; Bh=Whi; Bl=Wlo; }
    else { Ah=Qhi; Al=Qlo; Bh=Khi; Bl=Klo; }
    size_t rowbase = (size_t)t0*DM + h*HD;
    f32x4 acc[4][4];
    #pragma unroll
    for (int a=0;a<4;a++)
      #pragma unroll
      for (int b=0;b<4;b++) acc[a][b] = (f32x4){0.f,0.f,0.f,0.f};
    #pragma unroll 1
    for (int ks=0; ks<4; ++ks){
      bf16x8 ah[4], al[4], bh[4], bl[4];
      #pragma unroll
      for (int f=0; f<4; f++){
        size_t off = rowbase + (size_t)(16*f + l15)*DM + ks*32 + l4*8;
        ah[f] = *(const bf16x8*)(Ah + off);
        al[f] = *(const bf16x8*)(Al + off);
        bh[f] = *(const bf16x8*)(Bh + off);
        bl[f] = *(const bf16x8*)(Bl + off);
      }
      #pragma unroll
      for (int fm=0; fm<4; fm++)
        #pragma unroll
        for (int fn=0; fn<4; fn++){
          acc[fm][fn] = MFMA16(ah[fm], bh[fn], acc[fm][fn], 0,0,0);
          acc[fm][fn] = MFMA16(ah[fm], bl[fn], acc[fm][fn], 0,0,0);
          acc[fm][fn] = MFMA16(al[fm], bh[fn], acc[fm][fn], 0,0,0);
        }
    }
    #pragma unroll
    for (int fm=0; fm<4; fm++)
      #pragma unroll
      for (int fn=0; fn<4; fn++)
        #pragma unroll
        for (int e=0; e<4; e++)
          P[w][16*fm + l4*4 + e][16*fn + l15] = acc[fm][fn][e];
  }
  __syncthreads();

  // ---- build M (strictly-lower, beta-scaled) ----
  #pragma unroll 1
  for (int i=0;i<16;i++){
    int idx = i*256 + tid;
    int s = idx>>6, r = idx&63;
    M[s][r] = (s>r) ? P[0][s][r]*bet[r] : 0.f;
  }
  __syncthreads();

  // ---- solve: thread c<64 -> rhs_k col c (plane1), c>=64 -> rhs_w col c-64 (plane0) ----
  float x[64];
  int col = tid & 63;
  if (tid < 128){
    int pl = (tid < 64) ? 1 : 0;
    #pragma unroll
    for (int s=0;s<64;++s){
      float v = P[pl][s][col];
      x[s] = (s > col) ? v : 0.f;
    }
  }
  __syncthreads();   // reads of planes 0/1 done before overwrite
  if (tid < 128){
    #pragma unroll
    for (int s=1; s<64; ++s){
      float a0=0.f, a1=0.f, a2=0.f, a3=0.f;
      #pragma unroll
      for (int r=0; r<(s&~3); r+=4){
        a0 += M[s][r  ]*x[r  ];
        a1 += M[s][r+1]*x[r+1];
        a2 += M[s][r+2]*x[r+2];
        a3 += M[s][r+3]*x[r+3];
      }
      #pragma unroll
      for (int r=(s&~3); r<s; ++r) a0 += M[s][r]*x[r];
      x[s] -= (a0+a1)+(a2+a3);
    }
    #pragma unroll
    for (int s=0;s<64;++s) x[s] *= bet[s];
    int dpl = (tid < 64) ? 0 : 1;
    #pragma unroll
    for (int s=0;s<64;++s) P[dpl][col][s] = x[s];
  }
  __syncthreads();

  // ---- post stage (MFMA) ----
  // A-fragments D = tril(QW) from plane2
  bf16x8 Dh[2], Dl[2];
  {
    int t = 16*w + l15;
    #pragma unroll
    for (int ks=0; ks<2; ++ks){
      const float* p = &P[2][t][ks*32 + l4*8];
      U16x8 hh, ll;
      #pragma unroll
      for (int e=0;e<8;e++){
        int s = ks*32 + l4*8 + e;
        float v = (s<=t) ? p[e] : 0.f;
        u16 hv = f2bf(v);
        hh.us[e] = hv; ll.us[e] = f2bf(v - bf2f(hv));
      }
      Dh[ks] = hh.bf; Dl[ks] = ll.bf;
    }
  }
  int mrow = 16*w + l4*4;

  // P1: Adiag = QK + D*(-XkT)
  {
    float* outp = Adiag + (size_t)(h*32+I)*64*64;
    #pragma unroll 1
    for (int fn=0; fn<4; ++fn){
      f32x4 acc;
      #pragma unroll
      for (int e=0;e<4;e++) acc[e] = P[3][mrow+e][16*fn + l15];
      #pragma unroll
      for (int ks=0; ks<2; ++ks){
        const float* p = &P[0][16*fn+l15][ks*32 + l4*8];
        U16x8 bh, bl;
        #pragma unroll
        for (int e=0;e<8;e++){
          float v = -p[e];
          u16 hv = f2bf(v); bh.us[e]=hv; bl.us[e]=f2bf(v - bf2f(hv));
        }
        acc = MFMA16(Dh[ks], bh.bf, acc, 0,0,0);
        acc = MFMA16(Dh[ks], bl.bf, acc, 0,0,0);
        acc = MFMA16(Dl[ks], bh.bf, acc, 0,0,0);
      }
      #pragma unroll
      for (int e=0;e<4;e++) outp[(mrow+e)*64 + 16*fn + l15] = acc[e];
    }
  }
  // P2: -C -> Ch/Cl
  {
    #pragma unroll 1
    for (int fn=0; fn<4; ++fn){
      f32x4 acc = (f32x4){0.f,0.f,0.f,0.f};
      #pragma unroll
      for (int ks=0; ks<2; ++ks){
        const float* p = &P[1][16*fn+l15][ks*32 + l4*8];
        U16x8 bh, bl;
        #pragma unroll
        for (int e=0;e<8;e++){
          float v = -p[e];
          u16 hv = f2bf(v); bh.us[e]=hv; bl.us[e]=f2bf(v - bf2f(hv));
        }
        acc = MFMA16(Dh[ks], bh.bf, acc, 0,0,0);
        acc = MFMA16(Dh[ks], bl.bf, acc, 0,0,0);
        acc = MFMA16(Dl[ks], bh.bf, acc, 0,0,0);
      }
      int s = 16*fn + l15;
      float bt = bet[s];
      #pragma unroll
      for (int e=0;e<4;e++){
        int t = mrow + e;
        float Dts = (s<=t) ? P[2][t][s] : 0.f;
        float mc = -bt*(Dts + acc[e]);
        u16 hv = f2bf(mc);
        Ch[t][s] = hv;
        Cl[t][s] = f2bf(mc - bf2f(hv));
      }
    }
  }
  __syncthreads();
  // P3: Ktilde = K + (-XkT rows)*WT
  {
    bf16x8 Ah[2], Al[2];
    int j = 16*w + l15;
    #pragma unroll
    for (int ks=0; ks<2; ++ks){
      const float* p = &P[0][j][ks*32 + l4*8];
      U16x8 hh, ll;
      #pragma unroll
      for (int e=0;e<8;e++){
        float v = -p[e];
        u16 hv = f2bf(v); hh.us[e]=hv; ll.us[e]=f2bf(v - bf2f(hv));
      }
      Ah[ks] = hh.bf; Al[ks] = ll.bf;
    }
    f32x4 acc[8];
    #pragma unroll
    for (int fn=0; fn<8; ++fn)
      #pragma unroll
      for (int e=0;e<4;e++)
        acc[fn][e] = Kn[(size_t)(t0+mrow+e)*DM + h*HD + 16*fn + l15];
    #pragma unroll
    for (int ks=0; ks<2; ++ks)
      #pragma unroll
      for (int fn=0; fn<8; ++fn){
        bf16x8 b = *(const bf16x8*)&WT[16*fn+l15][ks*32 + l4*8];
        acc[fn] = MFMA16(Ah[ks], b, acc[fn], 0,0,0);
        acc[fn] = MFMA16(Al[ks], b, acc[fn], 0,0,0);
      }
    #pragma unroll
    for (int fn=0; fn<8; ++fn)
      #pragma unroll
      for (int e=0;e<4;e++)
        Ktb[((size_t)h*TLEN + t0+mrow+e)*HD + 16*fn + l15] = f2bf(acc[fn][e]);
  }
  // P4: Qtilde = Q + mC*WT
  {
    bf16x8 Ah[2], Al[2];
    int t = 16*w + l15;
    #pragma unroll
    for (int ks=0; ks<2; ++ks){
      Ah[ks] = *(const bf16x8*)&Ch[t][ks*32 + l4*8];
      Al[ks] = *(const bf16x8*)&Cl[t][ks*32 + l4*8];
    }
    f32x4 acc[8];
    #pragma unroll
    for (int fn=0; fn<8; ++fn)
      #pragma unroll
      for (int e=0;e<4;e++)
        acc[fn][e] = Qn[(size_t)(t0+mrow+e)*DM + h*HD + 16*fn + l15];
    #pragma unroll
    for (int ks=0; ks<2; ++ks)
      #pragma unroll
      for (int fn=0; fn<8; ++fn){
        bf16x8 b = *(const bf16x8*)&WT[16*fn+l15][ks*32 + l4*8];
        acc[fn] = MFMA16(Ah[ks], b, acc[fn], 0,0,0);
        acc[fn] = MFMA16(Al[ks], b, acc[fn], 0,0,0);
      }
    #pragma unroll
    for (int fn=0; fn<8; ++fn)
      #pragma unroll
      for (int e=0;e<4;e++)
        Qt[((size_t)h*TLEN + t0+mrow+e)*HD + 16*fn + l15] = f2bf(acc[fn][e]);
  }
}

// ------------- fused windowed attention: per (head, chunk I) -------------
__global__ __launch_bounds__(256) void attn_win(const u16* __restrict__ Qt, const u16* __restrict__ Ktb,
    const float* __restrict__ Adiag, const float* __restrict__ G,
    const u16* __restrict__ Vt, u16* __restrict__ obuf){
  int h = blockIdx.x>>5, I = blockIdx.x&31;
  int tid = threadIdx.x, lane = tid&63, w = tid>>6;
  int l15 = lane&15, l4 = lane>>4;
  __shared__ float S[64][136];
  __shared__ u16 P[64][136];

  if (I > 0){
    f32x4 acc4[4];
    #pragma unroll
    for (int f=0;f<4;f++) acc4[f] = (f32x4){0.f,0.f,0.f,0.f};
    #pragma unroll 1
    for (int ks=0; ks<4; ++ks){
      bf16x8 af = *(const bf16x8*)(Qt + ((size_t)h*TLEN + I*64 + 16*w + l15)*HD + ks*32 + l4*8);
      #pragma unroll
      for (int fn=0; fn<4; ++fn){
        bf16x8 bf = *(const bf16x8*)(Ktb + ((size_t)h*TLEN + (I-1)*64 + 16*fn + l15)*HD + ks*32 + l4*8);
        acc4[fn] = MFMA16(af, bf, acc4[fn], 0,0,0);
      }
    }
    #pragma unroll
    for (int fn=0; fn<4; ++fn)
      #pragma unroll
      for (int e=0;e<4;e++)
        S[16*w + l4*4 + e][16*fn + l15] = acc4[fn][e];
  }
  #pragma unroll 1
  for (int i=0;i<16;i++){
    int idx = i*256 + tid;
    int tq = idx>>6, j = idx&63;
    S[tq][64+j] = Adiag[((size_t)(h*32+I)*64 + tq)*64 + j];
    if (I == 0) S[tq][j] = 0.f;
  }
  __syncthreads();

  {
    int r = tid>>2, qd = tid&3, c0 = qd*32;
    int t = I*64 + r;
    float Gt = G[h*TLEN + t];
    const float scale = 0.08838834764831845f;
    int base = I*64 - 64;
    float lg[32];
    float mx = -1e30f;
    #pragma unroll
    for (int e=0;e<32;e++){
      int c = c0 + e;
      int j = base + c;
      float gj = G[h*TLEN + (j<0?0:j)];
      float v = (j>=0 && j<=t) ? (S[r][c]*scale + Gt - gj) : -1e30f;
      lg[e] = v;
      mx = fmaxf(mx, v);
    }
    mx = fmaxf(mx, __shfl_xor(mx, 1, 64));
    mx = fmaxf(mx, __shfl_xor(mx, 2, 64));
    float sum = 0.f;
    #pragma unroll
    for (int e=0;e<32;e++){ float p = __expf(lg[e]-mx); lg[e] = p; sum += p; }
    sum += __shfl_xor(sum, 1, 64);
    sum += __shfl_xor(sum, 2, 64);
    float inv = 1.f/sum;
    #pragma unroll
    for (int e8=0;e8<4;e8++){
      U16x8 u;
      #pragma unroll
      for (int e=0;e<8;e++) u.us[e] = f2bf(lg[e8*8+e]*inv);
      *(uint4*)&P[r][c0 + e8*8] = u.u4;
    }
  }
  __syncthreads();

  {
    f32x4 acc[8];
    #pragma unroll
    for (int f=0;f<8;f++) acc[f] = (f32x4){0.f,0.f,0.f,0.f};
    #pragma unroll 1
    for (int ks=0; ks<4; ++ks){
      bf16x8 pa = *(const bf16x8*)&P[16*w + l15][ks*32 + l4*8];
      int jb = (I-1)*64 + ks*32 + l4*8;
      if (jb < 0) jb = 0;
      #pragma unroll
      for (int fd=0; fd<8; ++fd){
        bf16x8 vb = *(const bf16x8*)(Vt + ((size_t)(h*HD + l15 + 16*fd))*TLEN + jb);
        acc[fd] = MFMA16(pa, vb, acc[fd], 0,0,0);
      }
    }
    #pragma unroll
    for (int fd=0; fd<8; ++fd)
      #pragma unroll
      for (int e=0;e<4;e++)
        obuf[(size_t)(I*64 + 16*w + l4*4 + e)*DM + h*HD + l15 + 16*fd] = f2bf(acc[fd][e]);
  }
}

extern "C" void kernel_launch(void* const* d_in, const int* in_sizes, int n_in,
                              void* d_out, int out_size, void* d_ws, size_t ws_size,
                              hipStream_t stream){
  const float* x     = (const float*)d_in[0];
  const float* Wq    = (const float*)d_in[1];
  const float* Wk    = (const float*)d_in[2];
  const float* Wv    = (const float*)d_in[3];
  const float* Ww    = (const float*)d_in[4];
  const float* Wbeta = (const float*)d_in[5];
  const float* Wg    = (const float*)d_in[6];
  const float* Wo    = (const float*)d_in[7];
  const float* convw = (const float*)d_in[8];
  const float* qnw   = (const float*)d_in[9];
  const float* knw   = (const float*)d_in[10];

  char* ws = (char*)d_ws;
  size_t off = 0;
  auto take = [&](size_t n)->char*{ char* p = ws + off; off += (n + 255) & ~(size_t)255; return p; };

  u16*  xb    = (u16*)take((size_t)TLEN*DM*2);      // aliased later by obuf
  u16*  WqT   = (u16*)take((size_t)DM*DM*2);
  u16*  WkT   = (u16*)take((size_t)DM*DM*2);
  u16*  WvT   = (u16*)take((size_t)DM*DM*2);
  u16*  WwT   = (u16*)take((size_t)DM*DM*2);
  u16*  WoT   = (u16*)take((size_t)DM*DM*2);
  float* Qn   = (float*)take((size_t)TLEN*DM*4);
  float* Kn   = (float*)take((size_t)TLEN*DM*4);
  float* Vraw = (float*)take((size_t)TLEN*DM*4);    // aliased later by Adiag
  float* Wpre = (float*)take((size_t)TLEN*DM*4);
  u16*  Vt    = (u16*)take((size_t)DM*TLEN*2);
  float* xWb  = (float*)take((size_t)TLEN*8*4);
  float* xWg  = (float*)take((size_t)TLEN*8*4);
  float* betaB= (float*)take((size_t)NH*TLEN*4);
  float* GB   = (float*)take((size_t)NH*TLEN*4);
  u16*  Qt    = (u16*)take((size_t)NH*TLEN*HD*2);
  u16*  Ktb   = (u16*)take((size_t)NH*TLEN*HD*2);
  u16*  Whi   = (u16*)take((size_t)TLEN*DM*2);
  u16*  Wlo   = (u16*)take((size_t)TLEN*DM*2);
  u16*  Khi   = (u16*)take((size_t)TLEN*DM*2);
  u16*  Klo   = (u16*)take((size_t)TLEN*DM*2);
  u16*  Qhi   = (u16*)take((size_t)TLEN*DM*2);
  u16*  Qlo   = (u16*)take((size_t)TLEN*DM*2);

  float* Adiag = (float*)Vraw;   // 4 MB needed; Vraw dead after Vt transpose
  u16*  obuf  = xb;              // 4 MB; xb dead after the projection GEMMs

  cast_f32_bf16<<<dim3(TLEN*DM/(256*8)), dim3(256), 0, stream>>>(x, xb, TLEN*DM);
  transpose_cast5<<<dim3(16,16,5), dim3(256), 0, stream>>>(Wq, Wk, Wv, Ww, Wo, WqT, WkT, WvT, WwT, WoT);

  // all 4 projections in ONE launch: 512 blocks, global_load_lds staging
  gemm4<<<dim3(32,16), dim3(256), 0, stream>>>(xb, WqT, WkT, WvT, WwT, Qn, Kn, Vraw, Wpre);

  proj_small<<<dim3(TLEN/4), dim3(256), 0, stream>>>(x, Wbeta, Wg, xWb, xWg);
  scan_g<<<dim3(1), dim3(512), 0, stream>>>(xWb, xWg, betaB, GB);

  rms_hilo<<<dim3(2*TLEN*NH), dim3(64), 0, stream>>>(Qn, Kn, qnw, knw, Qhi, Qlo, Khi, Klo);
  conv_hilo<<<dim3(TLEN), dim3(256), 0, stream>>>(Wpre, convw, Whi, Wlo);
  transpose_cast<<<dim3(16,32), dim3(256), 0, stream>>>(Vraw, Vt, TLEN, DM);   // Vraw dead after this

  chunk_fused<<<dim3(256), dim3(256), 0, stream>>>(Whi, Wlo, Khi, Klo, Qhi, Qlo,
                                                   Qn, Kn, betaB, Adiag, Qt, Ktb);

  attn_win<<<dim3(256), dim3(256), 0, stream>>>(Qt, Ktb, Adiag, GB, Vt, obuf);

  // FINAL PROJECTION — d_out is FLOAT32; single-B use of gemm4 (bsel always 0)
  gemm4<<<dim3(8,16), dim3(256), 0, stream>>>(obuf, WoT, WoT, WoT, WoT,
                                              (float*)d_out, (float*)d_out, (float*)d_out, (float*)d_out);
}